// Round 14
// baseline (603.140 us; speedup 1.0000x reference)
//
#include <hip/hip_runtime.h>
#include <hip/hip_fp16.h>

#define N_NODES 25000
#define M_PAD   25024            // multiple of 16 (1564 tiles)
#define N_TILES 1564
#define N_EDGES 300000
#define IN_DIM  32
#define EDFD    16
#define HIDD    256
#define HEADS   4
#define NACT    16
#define NGRAPH  64
#define KWIRE   1024
#define POOL_NB 64

typedef _Float16 half8v __attribute__((ext_vector_type(8)));
typedef __attribute__((ext_vector_type(4))) float f32x4;

// pin each 32-bit lane of a float4 in a VGPR (opaque to the scheduler -> no remat/refetch)
__device__ __forceinline__ void pin4(float4& v) {
    asm volatile("" : "+v"(v.x), "+v"(v.y), "+v"(v.z), "+v"(v.w));
}

// ---------------------------------------------------------------- helpers
__device__ __forceinline__ float leaky(float v) { return v > 0.f ? v : 0.2f * v; }
__device__ __forceinline__ int fkey(float f) {
    int b = __float_as_int(f);
    b ^= (b >> 31) & 0x7fffffff;
    return b;
}
__device__ __forceinline__ float funkey(int b) {
    b ^= (b >> 31) & 0x7fffffff;
    return __int_as_float(b);
}

// ---------------------------------------------------------------- CSR build (both directions)
__global__ __launch_bounds__(256) void k_deg2(const int* __restrict__ ei,
                                              int* __restrict__ deg,
                                              int* __restrict__ deg2) {
    int e = blockIdx.x * 256 + threadIdx.x;
    if (e >= N_EDGES) return;
    atomicAdd(&deg[ei[N_EDGES + e]], 1);
    atomicAdd(&deg2[ei[e]], 1);
}

__global__ __launch_bounds__(256) void k_scan2(const int* __restrict__ degA, int* __restrict__ rpA,
                                               const int* __restrict__ degB, int* __restrict__ rpB) {
    const int* deg = blockIdx.x ? degB : degA;
    int* rowptr    = blockIdx.x ? rpB : rpA;
    __shared__ int part[256];
    int t = threadIdx.x;
    const int CH = 98;
    int base = t * CH;
    int s = 0;
    for (int i = 0; i < CH; ++i) {
        int idx = base + i;
        if (idx < N_NODES) s += deg[idx];
    }
    part[t] = s;
    __syncthreads();
    if (t == 0) {
        int run = 0;
        for (int i = 0; i < 256; ++i) { int v = part[i]; part[i] = run; run += v; }
    }
    __syncthreads();
    int run = part[t];
    for (int i = 0; i < CH; ++i) {
        int idx = base + i;
        if (idx < N_NODES) { rowptr[idx] = run; run += deg[idx]; }
    }
    if (N_NODES >= base && N_NODES < base + CH) rowptr[N_NODES] = run;
}

__global__ __launch_bounds__(256) void k_scatter2(const int* __restrict__ ei,
                                                  const int* __restrict__ rowptr,
                                                  const int* __restrict__ rowptr2,
                                                  int* __restrict__ cursor,
                                                  int* __restrict__ cursor2,
                                                  int* __restrict__ csrc,
                                                  int* __restrict__ epos,
                                                  int* __restrict__ cdst,
                                                  int* __restrict__ epos2) {
    int e = blockIdx.x * 256 + threadIdx.x;
    if (e >= N_EDGES) return;
    int src = ei[e], dst = ei[N_EDGES + e];
    int p1 = atomicAdd(&cursor[dst], 1);
    int r1 = rowptr[dst] + p1;
    csrc[r1] = src;
    epos[e] = r1;
    int p2 = atomicAdd(&cursor2[src], 1);
    int r2 = rowptr2[src] + p2;
    cdst[r2] = dst;
    epos2[e] = r2;
}

// ---------------------------------------------------------------- weight prep
// enc_w2 perm: wtt[co][i], co=j*32+o
__global__ __launch_bounds__(256) void k_w2perm(const float* __restrict__ w2,
                                                __half* __restrict__ Wt) {
    int idx = blockIdx.x * 256 + threadIdx.x;   // co*32 + i
    if (idx >= 32 * 1024) return;
    int co = idx >> 5, i = idx & 31;
    Wt[idx] = __float2half(w2[(co >> 5) * 1024 + i * 32 + (co & 31)]);
}

// head-mean-folded weights: Wb1[d][k], k=h*32+i ; value 0.25*W1[i, h*256+d]
__global__ __launch_bounds__(256) void k_wb1(const float* __restrict__ W1,
                                             __half* __restrict__ Wb) {
    int idx = blockIdx.x * 256 + threadIdx.x;   // d*128+k
    if (idx >= 256 * 128) return;
    int d = idx >> 7, k = idx & 127;
    int h = k >> 5, i = k & 31;
    Wb[idx] = __float2half(0.25f * W1[i * 1024 + h * 256 + d]);
}

// Wb2[d][k], k=h*256+i ; value 0.25*W2[i, h*256+d]
__global__ __launch_bounds__(256) void k_wb2(const float* __restrict__ W2,
                                             __half* __restrict__ Wb) {
    int idx = blockIdx.x * 256 + threadIdx.x;   // d*1024+k
    if (idx >= 256 * 1024) return;
    int d = idx >> 10, k = idx & 1023;
    int h = k >> 8, i = k & 255;
    Wb[idx] = __float2half(0.25f * W2[i * 1024 + h * 256 + d]);
}

__global__ __launch_bounds__(128) void k_wa1(const float* __restrict__ W1,
                                             const float* __restrict__ asrc,
                                             const float* __restrict__ adst,
                                             float* __restrict__ wa,
                                             float* __restrict__ wd) {
    int t = threadIdx.x;            // h*32+i
    int h = t >> 5, i = t & 31;
    float s = 0.f, sd = 0.f;
    for (int d = 0; d < 256; ++d) {
        float w = W1[i * 1024 + h * 256 + d];
        s  += w * asrc[h * 256 + d];
        sd += w * adst[h * 256 + d];
    }
    wa[t] = s; wd[t] = sd;
}

__global__ __launch_bounds__(256) void k_wa2(const float* __restrict__ W2,
                                             const float* __restrict__ asrc,
                                             const float* __restrict__ adst,
                                             float* __restrict__ wa,
                                             float* __restrict__ wd) {
    int idx = blockIdx.x * 256 + threadIdx.x;   // h*256+i
    if (idx >= 1024) return;
    int h = idx >> 8, i = idx & 255;
    float s = 0.f, sd = 0.f;
    for (int d = 0; d < 256; ++d) {
        float w = W2[i * 1024 + h * 256 + d];
        s  += w * asrc[h * 256 + d];
        sd += w * adst[h * 256 + d];
    }
    wa[idx] = s; wd[idx] = sd;
}

__global__ __launch_bounds__(256) void k_xcvt(const float* __restrict__ x,
                                              const float* __restrict__ b2,
                                              __half* __restrict__ xf,
                                              float* __restrict__ xb) {
    int idx = blockIdx.x * 256 + threadIdx.x;
    if (idx >= N_NODES * 32) return;
    int n = idx >> 5, o = idx & 31;
    xf[idx] = __float2half(x[idx]);
    float s = 0.f;
    for (int i = 0; i < 32; ++i) s += x[n * 32 + i] * b2[i * 32 + o];
    xb[idx] = s;
}

// ---------------------------------------------------------------- NNConv
__global__ __launch_bounds__(256) void k_hedge(const float* __restrict__ ea,
                                               const float* __restrict__ w1,
                                               const float* __restrict__ b1,
                                               const int* __restrict__ epos2,
                                               __half* __restrict__ hEs) {
    int t = threadIdx.x;
    int eg = t >> 5, o = t & 31;
    int e = blockIdx.x * 8 + eg;
    if (e >= N_EDGES) return;
    float a = b1[o];
    for (int k = 0; k < EDFD; ++k) a += ea[e * EDFD + k] * w1[k * 32 + o];
    hEs[(size_t)epos2[e] * 32 + o] = __float2half(fmaxf(a, 0.f));
}

__global__ __launch_bounds__(256) void k_msg2(const int* __restrict__ rowptr2,
                                              const int* __restrict__ cdst,
                                              const __half* __restrict__ hEs,
                                              const __half* __restrict__ T,
                                              const float* __restrict__ xb,
                                              float* __restrict__ agg) {
    int g = threadIdx.x >> 5, o = threadIdx.x & 31;
    int src = blockIdx.x * 8 + g;
    if (src >= N_NODES) return;
    int r0 = rowptr2[src], r1 = rowptr2[src + 1];
    if (r0 == r1) return;
    float tcol[32];
    const __half* Tp = T + (size_t)src * 1024 + o;
    #pragma unroll
    for (int j = 0; j < 32; ++j) tcol[j] = __half2float(Tp[j * 32]);
    float xbv = xb[src * 32 + o];
    for (int r = r0; r < r1; ++r) {
        int dst = cdst[r];
        const __half2* hp2 = (const __half2*)(hEs + (size_t)r * 32);
        float m = xbv;
        #pragma unroll
        for (int jj = 0; jj < 16; ++jj) {
            float2 hv = __half22float2(hp2[jj]);
            m += hv.x * tcol[2 * jj] + hv.y * tcol[2 * jj + 1];
        }
        atomicAdd(&agg[dst * 32 + o], m);
    }
}

// h0 = relu(agg/deg + x@root_w + bias) -> fp16, fused layer1 es/ed/mkey
__global__ __launch_bounds__(256) void k_h0e(const float* __restrict__ x,
                                             const float* __restrict__ root_w,
                                             const float* __restrict__ nn_bias,
                                             const float* __restrict__ agg,
                                             const int* __restrict__ rowptr,
                                             const float* __restrict__ wa,
                                             const float* __restrict__ wd,
                                             __half* __restrict__ h0f,
                                             float* __restrict__ es,
                                             float* __restrict__ ed,
                                             int* __restrict__ mkey) {
    int t = threadIdx.x;
    int ng = t >> 5, o = t & 31;
    int n = blockIdx.x * 8 + ng;
    if (n >= N_NODES) return;
    float s = nn_bias[o];
    for (int k = 0; k < IN_DIM; ++k) s += x[n * IN_DIM + k] * root_w[k * 32 + o];
    float c = fmaxf((float)(rowptr[n + 1] - rowptr[n]), 1.f);
    s += agg[n * IN_DIM + o] / c;
    float v = fmaxf(s, 0.f);
    h0f[n * IN_DIM + o] = __float2half(v);
    #pragma unroll
    for (int h = 0; h < 4; ++h) {
        float ss = v * wa[h * 32 + o];
        float dd = v * wd[h * 32 + o];
        #pragma unroll
        for (int off = 16; off; off >>= 1) {
            ss += __shfl_down(ss, off, 32);
            dd += __shfl_down(dd, off, 32);
        }
        if (o == 0) {
            es[n * 4 + h] = ss; ed[n * 4 + h] = dd;
            mkey[n * 4 + h] = fkey(leaky(ss + dd));
        }
    }
}

// ---------------------------------------------------------------- GEMM 1: T = xf @ wtt^T, out [M,1024] fp16
__global__ __launch_bounds__(256, 2) void k_gemT(const __half* __restrict__ A,
                                                 const __half* __restrict__ Wt,
                                                 __half* __restrict__ C) {
    __shared__ __half cst[4][16 * 36];
    int t = threadIdx.x, wid = t >> 6, lane = t & 63;
    int lr = lane & 15, lk = (lane >> 4) * 8;

    int bid = blockIdx.x;
    int xcd = bid & 7, j = bid >> 3;
    int sx = j & 31;
    int y = ((j >> 5) << 3) | xcd;            // 0..103
    int n0 = sx * 32;

    half8v bfr[2];
    #pragma unroll
    for (int c = 0; c < 2; ++c) {
        float4 raw = *(const float4*)(Wt + (size_t)(n0 + c * 16 + lr) * 32 + lk);
        pin4(raw);
        bfr[c] = __builtin_bit_cast(half8v, raw);
    }

    int tb = (y * 4 + wid) * 4;
    for (int pp = 0; pp < 4; pp += 2) {
        int tA = tb + pp;
        if (tA >= N_TILES) break;
        int mA = tA * 16, mB = mA + 16;
        half8v aA = *(const half8v*)(A + (size_t)(mA + lr) * 32 + lk);
        half8v aB = *(const half8v*)(A + (size_t)(mB + lr) * 32 + lk);
        f32x4 acc[2][2];
        #pragma unroll
        for (int i = 0; i < 2; ++i)
            #pragma unroll
            for (int c = 0; c < 2; ++c)
                acc[i][c] = (f32x4){0.f, 0.f, 0.f, 0.f};
        acc[0][0] = __builtin_amdgcn_mfma_f32_16x16x32_f16(aA, bfr[0], acc[0][0], 0, 0, 0);
        acc[0][1] = __builtin_amdgcn_mfma_f32_16x16x32_f16(aA, bfr[1], acc[0][1], 0, 0, 0);
        acc[1][0] = __builtin_amdgcn_mfma_f32_16x16x32_f16(aB, bfr[0], acc[1][0], 0, 0, 0);
        acc[1][1] = __builtin_amdgcn_mfma_f32_16x16x32_f16(aB, bfr[1], acc[1][1], 0, 0, 0);

        int rbase = (lane >> 4) * 4;
        #pragma unroll
        for (int ti = 0; ti < 2; ++ti) {
            #pragma unroll
            for (int c = 0; c < 2; ++c)
                #pragma unroll
                for (int r = 0; r < 4; ++r)
                    cst[wid][(rbase + r) * 36 + c * 16 + lr] = __float2half(acc[ti][c][r]);
            int m0 = ti ? mB : mA;
            #pragma unroll
            for (int p = 0; p < 2; ++p) {
                int row = p * 8 + (lane >> 3), hb = lane & 7;
                float2 v = *(const float2*)((const char*)&cst[wid][0] + row * 72 + hb * 8);
                *(float2*)((char*)C + ((size_t)(m0 + row) * 1024 + n0) * 2 + hb * 8) = v;
            }
        }
    }
}

// ---------------------------------------------------------------- GEMM 2: head-mean-folded, out [M,256]
// C = relu(A[M,K] @ Wt[256,K]^T + bias). OT = __half (h1) or float (h2). K in {128,1024}.
template <int K, typename OT>
__global__ __launch_bounds__(256, 2) void k_gemmo(const __half* __restrict__ A,
                                                  const __half* __restrict__ Wt,
                                                  const float* __restrict__ bias,
                                                  OT* __restrict__ C) {
    constexpr int KC  = (K > 256) ? 4 : 1;      // chunks
    constexpr int CK  = K / KC;                 // cols per chunk
    constexpr int KSC = CK / 32;
    __shared__ float cst[4][16 * 36];
    int t = threadIdx.x, wid = t >> 6, lane = t & 63;
    int lr = lane & 15, lk = (lane >> 4) * 8;
    int strip = blockIdx.x & 7, y = blockIdx.x >> 3;
    int n0 = strip * 32;
    float bv0 = bias[n0 + lr], bv1 = bias[n0 + 16 + lr];

    int tb = (y * 4 + wid) * 4;
    for (int pp = 0; pp < 4; pp += 2) {
        int tA = tb + pp;
        if (tA >= N_TILES) break;
        int mA = tA * 16, mB = mA + 16;
        f32x4 acc[2][2];
        #pragma unroll
        for (int i = 0; i < 2; ++i)
            #pragma unroll
            for (int c = 0; c < 2; ++c)
                acc[i][c] = (f32x4){0.f, 0.f, 0.f, 0.f};

        for (int kc = 0; kc < KC; ++kc) {
            half8v bfr[KSC][2];
            #pragma unroll
            for (int ks = 0; ks < KSC; ++ks)
                #pragma unroll
                for (int c = 0; c < 2; ++c) {
                    float4 raw = *(const float4*)(Wt + (size_t)(n0 + c * 16 + lr) * K + kc * CK + ks * 32 + lk);
                    pin4(raw);
                    bfr[ks][c] = __builtin_bit_cast(half8v, raw);
                }
            const __half* pA = A + (size_t)(mA + lr) * K + kc * CK + lk;
            const __half* pB = A + (size_t)(mB + lr) * K + kc * CK + lk;
            #pragma unroll
            for (int ks = 0; ks < KSC; ++ks) {
                half8v aA = *(const half8v*)(pA + (size_t)ks * 32);
                half8v aB = *(const half8v*)(pB + (size_t)ks * 32);
                acc[0][0] = __builtin_amdgcn_mfma_f32_16x16x32_f16(aA, bfr[ks][0], acc[0][0], 0, 0, 0);
                acc[0][1] = __builtin_amdgcn_mfma_f32_16x16x32_f16(aA, bfr[ks][1], acc[0][1], 0, 0, 0);
                acc[1][0] = __builtin_amdgcn_mfma_f32_16x16x32_f16(aB, bfr[ks][0], acc[1][0], 0, 0, 0);
                acc[1][1] = __builtin_amdgcn_mfma_f32_16x16x32_f16(aB, bfr[ks][1], acc[1][1], 0, 0, 0);
            }
        }

        int rbase = (lane >> 4) * 4;
        #pragma unroll
        for (int ti = 0; ti < 2; ++ti) {
            #pragma unroll
            for (int c = 0; c < 2; ++c)
                #pragma unroll
                for (int r = 0; r < 4; ++r)
                    cst[wid][(rbase + r) * 36 + c * 16 + lr] =
                        fmaxf(acc[ti][c][r] + (c ? bv1 : bv0), 0.f);
            int m0 = ti ? mB : mA;
            int row = lane >> 2, cg = lane & 3;   // 16 rows x 4 col-groups of 8
            const float* sp = &cst[wid][row * 36 + cg * 8];
            if constexpr (sizeof(OT) == 2) {
                __half2 o0 = __float22half2_rn(make_float2(sp[0], sp[1]));
                __half2 o1 = __float22half2_rn(make_float2(sp[2], sp[3]));
                __half2 o2 = __float22half2_rn(make_float2(sp[4], sp[5]));
                __half2 o3 = __float22half2_rn(make_float2(sp[6], sp[7]));
                float4 v = make_float4(__uint_as_float(*(unsigned*)&o0), __uint_as_float(*(unsigned*)&o1),
                                       __uint_as_float(*(unsigned*)&o2), __uint_as_float(*(unsigned*)&o3));
                *(float4*)((__half*)C + (size_t)(m0 + row) * 256 + n0 + cg * 8) = v;
            } else {
                float4 v0 = make_float4(sp[0], sp[1], sp[2], sp[3]);
                float4 v1 = make_float4(sp[4], sp[5], sp[6], sp[7]);
                float* cp = (float*)C + (size_t)(m0 + row) * 256 + n0 + cg * 8;
                *(float4*)cp = v0;
                *(float4*)(cp + 4) = v1;
            }
        }
    }
}

// ---------------------------------------------------------------- attention scalars
__global__ __launch_bounds__(256) void k_esed2(const __half* __restrict__ h1f,
                                               const float* __restrict__ wa,
                                               const float* __restrict__ wd,
                                               float* __restrict__ es,
                                               float* __restrict__ ed,
                                               int* __restrict__ mkey) {
    int n = blockIdx.x;
    int h = threadIdx.x >> 6, lane = threadIdx.x & 63;
    float s = 0.f, d2 = 0.f;
    for (int d = lane; d < 256; d += 64) {
        float v = __half2float(h1f[(size_t)n * 256 + d]);
        s  += v * wa[h * 256 + d];
        d2 += v * wd[h * 256 + d];
    }
    #pragma unroll
    for (int off = 32; off; off >>= 1) {
        s  += __shfl_down(s, off);
        d2 += __shfl_down(d2, off);
    }
    if (lane == 0) {
        es[n * 4 + h] = s; ed[n * 4 + h] = d2;
        mkey[n * 4 + h] = fkey(leaky(s + d2));
    }
}

__global__ __launch_bounds__(256) void k_mmax(const int* __restrict__ ei,
                                              const float* __restrict__ es,
                                              const float* __restrict__ ed,
                                              int* __restrict__ mkey) {
    int idx = blockIdx.x * 256 + threadIdx.x;
    if (idx >= N_EDGES * 4) return;
    int e = idx >> 2, h = idx & 3;
    int src = ei[e], dst = ei[N_EDGES + e];
    atomicMax(&mkey[dst * 4 + h], fkey(leaky(es[src * 4 + h] + ed[dst * 4 + h])));
}

__global__ __launch_bounds__(256) void k_watt(const int* __restrict__ ei,
                                              const int* __restrict__ epos,
                                              const float* __restrict__ es,
                                              const float* __restrict__ ed,
                                              const int* __restrict__ mkey,
                                              float* __restrict__ wv,
                                              float* __restrict__ den) {
    int idx = blockIdx.x * 256 + threadIdx.x;
    if (idx >= N_EDGES * 4) return;
    int e = idx >> 2, h = idx & 3;
    int src = ei[e], dst = ei[N_EDGES + e];
    float v = leaky(es[src * 4 + h] + ed[dst * 4 + h]);
    float w = __expf(v - funkey(mkey[dst * 4 + h]));
    wv[(size_t)epos[e] * 4 + h] = w;
    atomicAdd(&den[dst * 4 + h], w);
}

// ---------------------------------------------------------------- pre-GEMM aggregation
__global__ __launch_bounds__(256) void k_agg1(const int* __restrict__ rowptr,
                                              const int* __restrict__ csrc,
                                              const float* __restrict__ es,
                                              const float* __restrict__ ed,
                                              const int* __restrict__ mkey,
                                              const float* __restrict__ denb,
                                              const float* __restrict__ wv,
                                              const __half* __restrict__ h0f,
                                              __half* __restrict__ agg0) {
    int dst = blockIdx.x * 4 + (threadIdx.x >> 6);
    if (dst >= N_NODES) return;
    int lane = threadIdx.x & 63;
    int h = lane >> 4, i2 = lane & 15;
    float m = funkey(mkey[dst * 4 + h]);
    float vself = leaky(es[dst * 4 + h] + ed[dst * 4 + h]);
    float ws = __expf(vself - m);
    float dn = denb[dst * 4 + h] + ws;
    int r0 = rowptr[dst], r1 = rowptr[dst + 1];

    __half2 hv = *(const __half2*)(h0f + (size_t)dst * 32 + i2 * 2);
    float2 f = __half22float2(hv);
    float ax = ws * f.x, ay = ws * f.y;
    for (int r = r0; r < r1; ++r) {
        int src = csrc[r];
        float w = wv[(size_t)r * 4 + h];
        __half2 sv = *(const __half2*)(h0f + (size_t)src * 32 + i2 * 2);
        float2 g = __half22float2(sv);
        ax += w * g.x; ay += w * g.y;
    }
    float inv = 1.f / (dn + 1e-16f);
    *(__half2*)(agg0 + (size_t)dst * 128 + h * 32 + i2 * 2) =
        __float22half2_rn(make_float2(ax * inv, ay * inv));
}

__global__ __launch_bounds__(256) void k_agg2(const int* __restrict__ rowptr,
                                              const int* __restrict__ csrc,
                                              const float* __restrict__ es,
                                              const float* __restrict__ ed,
                                              const int* __restrict__ mkey,
                                              const float* __restrict__ denb,
                                              const float* __restrict__ wv,
                                              const __half* __restrict__ h1f,
                                              __half* __restrict__ agg1) {
    int dst = blockIdx.x * 4 + (threadIdx.x >> 6);
    if (dst >= N_NODES) return;
    int lane = threadIdx.x & 63;
    float ws[4], dn[4];
    #pragma unroll
    for (int h = 0; h < 4; ++h) {
        float m = funkey(mkey[dst * 4 + h]);
        float vself = leaky(es[dst * 4 + h] + ed[dst * 4 + h]);
        ws[h] = __expf(vself - m);
        dn[h] = denb[dst * 4 + h] + ws[h];
    }
    int r0 = rowptr[dst], r1 = rowptr[dst + 1];

    float acc[4][4];
    {
        float2 q = *(const float2*)(h1f + (size_t)dst * 256 + lane * 4);
        const __half2* hq = (const __half2*)&q;
        float2 f0 = __half22float2(hq[0]), f1 = __half22float2(hq[1]);
        #pragma unroll
        for (int h = 0; h < 4; ++h) {
            acc[h][0] = ws[h] * f0.x; acc[h][1] = ws[h] * f0.y;
            acc[h][2] = ws[h] * f1.x; acc[h][3] = ws[h] * f1.y;
        }
    }
    for (int r = r0; r < r1; ++r) {
        int src = csrc[r];
        float4 w4 = *(const float4*)(wv + (size_t)r * 4);
        float2 q = *(const float2*)(h1f + (size_t)src * 256 + lane * 4);
        const __half2* hq = (const __half2*)&q;
        float2 f0 = __half22float2(hq[0]), f1 = __half22float2(hq[1]);
        acc[0][0] += w4.x * f0.x; acc[0][1] += w4.x * f0.y; acc[0][2] += w4.x * f1.x; acc[0][3] += w4.x * f1.y;
        acc[1][0] += w4.y * f0.x; acc[1][1] += w4.y * f0.y; acc[1][2] += w4.y * f1.x; acc[1][3] += w4.y * f1.y;
        acc[2][0] += w4.z * f0.x; acc[2][1] += w4.z * f0.y; acc[2][2] += w4.z * f1.x; acc[2][3] += w4.z * f1.y;
        acc[3][0] += w4.w * f0.x; acc[3][1] += w4.w * f0.y; acc[3][2] += w4.w * f1.x; acc[3][3] += w4.w * f1.y;
    }
    #pragma unroll
    for (int h = 0; h < 4; ++h) {
        float inv = 1.f / (dn[h] + 1e-16f);
        __half2 o0 = __float22half2_rn(make_float2(acc[h][0] * inv, acc[h][1] * inv));
        __half2 o1 = __float22half2_rn(make_float2(acc[h][2] * inv, acc[h][3] * inv));
        __half2* op = (__half2*)(agg1 + (size_t)dst * 1024 + h * 256 + lane * 4);
        op[0] = o0; op[1] = o1;
    }
}

// ---------------------------------------------------------------- heads
__global__ __launch_bounds__(256) void k_wire(const int* __restrict__ wm,
                                              const float* __restrict__ h2,
                                              const float* __restrict__ ww,
                                              const float* __restrict__ wb,
                                              float* __restrict__ out) {
    int k = blockIdx.x * 4 + (threadIdx.x >> 6);
    int lane = threadIdx.x & 63;
    if (k >= KWIRE) return;
    int n = wm[k];
    float s = 0.f;
    for (int d = lane; d < 256; d += 64) s += h2[(size_t)n * 256 + d] * ww[d];
    #pragma unroll
    for (int off = 32; off; off >>= 1) s += __shfl_down(s, off);
    if (lane == 0) out[k] = s + wb[0];
}

__global__ __launch_bounds__(256) void k_pool(const float* __restrict__ h2,
                                              const int* __restrict__ batch,
                                              float* __restrict__ pooled,
                                              float* __restrict__ gcnt) {
    int n0 = blockIdx.x * POOL_NB;
    int n1 = n0 + POOL_NB; if (n1 > N_NODES) n1 = N_NODES;
    int d = threadIdx.x;
    int cur = batch[n0];
    float acc = 0.f, cnt = 0.f;
    for (int n = n0; n < n1; ++n) {
        int g = batch[n];
        if (g != cur) {
            atomicAdd(&pooled[cur * 256 + d], acc);
            if (d == 0) atomicAdd(&gcnt[cur], cnt);
            acc = 0.f; cnt = 0.f; cur = g;
        }
        acc += h2[(size_t)n * 256 + d];
        cnt += 1.f;
    }
    atomicAdd(&pooled[cur * 256 + d], acc);
    if (d == 0) atomicAdd(&gcnt[cur], cnt);
}

__global__ __launch_bounds__(256) void k_act(const float* __restrict__ pooled,
                                             const float* __restrict__ gcnt,
                                             const float* __restrict__ aw,
                                             const float* __restrict__ ab,
                                             float* __restrict__ out) {
    int u = blockIdx.x * 4 + (threadIdx.x >> 6);
    int lane = threadIdx.x & 63;
    if (u >= NGRAPH * NACT) return;
    int g = u >> 4, a = u & 15;
    float c = fmaxf(gcnt[g], 1.f);
    float s = 0.f;
    for (int d = lane; d < 256; d += 64) s += pooled[g * 256 + d] * aw[d * 16 + a];
    #pragma unroll
    for (int off = 32; off; off >>= 1) s += __shfl_down(s, off);
    if (lane == 0) out[KWIRE + u] = s / c + ab[a];
}

// ---------------------------------------------------------------- launch
extern "C" void kernel_launch(void* const* d_in, const int* in_sizes, int n_in,
                              void* d_out, int out_size, void* d_ws, size_t ws_size,
                              hipStream_t stream) {
    const float* x        = (const float*)d_in[0];
    const float* edge_attr= (const float*)d_in[1];
    const int*   wire_mask= (const int*)d_in[2];
    const int*   edge_idx = (const int*)d_in[3];
    const int*   batch    = (const int*)d_in[4];
    const float* enc_w1   = (const float*)d_in[5];
    const float* enc_b1   = (const float*)d_in[6];
    const float* enc_w2   = (const float*)d_in[7];
    const float* enc_b2   = (const float*)d_in[8];
    const float* root_w   = (const float*)d_in[9];
    const float* nn_bias  = (const float*)d_in[10];
    const float* gat1_w   = (const float*)d_in[11];
    const float* gat1_asrc= (const float*)d_in[12];
    const float* gat1_adst= (const float*)d_in[13];
    const float* gat1_b   = (const float*)d_in[14];
    const float* gat2_w   = (const float*)d_in[15];
    const float* gat2_asrc= (const float*)d_in[16];
    const float* gat2_adst= (const float*)d_in[17];
    const float* gat2_b   = (const float*)d_in[18];
    const float* wire_w   = (const float*)d_in[19];
    const float* wire_b   = (const float*)d_in[20];
    const float* act_w    = (const float*)d_in[21];
    const float* act_b    = (const float*)d_in[22];
    float* out = (float*)d_out;

    float* ws = (float*)d_ws;
    size_t off = 0;
    __half* T16   = (__half*)(ws + off); off += (size_t)M_PAD * 1024 / 2;
    __half* agg1f = (__half*)(ws + off); off += (size_t)M_PAD * 1024 / 2;
    __half* agg0f = (__half*)(ws + off); off += (size_t)M_PAD * 128 / 2;
    __half* h0f   = (__half*)(ws + off); off += (size_t)M_PAD * 32 / 2;
    __half* h1f   = (__half*)(ws + off); off += (size_t)M_PAD * 256 / 2;
    __half* xf    = (__half*)(ws + off); off += (size_t)M_PAD * 32 / 2;
    __half* hEs   = (__half*)(ws + off); off += (size_t)N_EDGES * 32 / 2;
    float* xb     = ws + off; off += 800000;
    float* agg    = ws + off; off += 800000;
    float* esb    = ws + off; off += 100000;
    float* edb    = ws + off; off += 100000;
    float* h2     = ws + off; off += (size_t)M_PAD * 256;
    float* pooled = ws + off; off += NGRAPH * 256;
    float* gcnt   = ws + off; off += NGRAPH;
    int* deg      = (int*)(ws + off); off += 25600;   // zero-region start
    int* deg2     = (int*)(ws + off); off += 25600;
    int* cursor   = (int*)(ws + off); off += 25600;
    int* cursor2  = (int*)(ws + off); off += 25600;   // zero-region end
    int* rowptr   = (int*)(ws + off); off += 25600;
    int* rowptr2  = (int*)(ws + off); off += 25600;
    int* csrc     = (int*)(ws + off); off += N_EDGES;
    int* epos     = (int*)(ws + off); off += N_EDGES;
    int* cdst     = (int*)(ws + off); off += N_EDGES;
    int* epos2    = (int*)(ws + off); off += N_EDGES;
    int* mkey     = (int*)(ws + off); off += 100000;
    float* den    = ws + off; off += 100000;
    float* wv     = ws + off; off += (size_t)N_EDGES * 4;
    __half* wtt   = (__half*)(ws + off); off += 16384;    // enc_w2 perm [1024][32]
    __half* wb1t  = (__half*)(ws + off); off += 16384;    // [256][128]
    __half* wb2t  = (__half*)(ws + off); off += 131072;   // [256][1024]
    float* wa1    = ws + off; off += 128;
    float* wd1    = ws + off; off += 128;
    float* wa2    = ws + off; off += 1024;
    float* wd2    = ws + off; off += 1024;

    const int EH = N_EDGES * 4;
    const int GBT = 3328;   // T-gemm: 8 xcd x 13 ygroups x 32 strips
    const int GBO = 784;    // out-256 gemms: 8 strips x 98 ygroups

    // ---- CSR build ----
    hipMemsetAsync(deg, 0, 4 * 25600 * sizeof(int), stream);
    k_deg2<<<(N_EDGES + 255) / 256, 256, 0, stream>>>(edge_idx, deg, deg2);
    k_scan2<<<2, 256, 0, stream>>>(deg, rowptr, deg2, rowptr2);
    k_scatter2<<<(N_EDGES + 255) / 256, 256, 0, stream>>>(edge_idx, rowptr, rowptr2,
                                                          cursor, cursor2, csrc, epos, cdst, epos2);

    // ---- weight prep ----
    k_w2perm<<<(32 * 1024 + 255) / 256, 256, 0, stream>>>(enc_w2, wtt);
    k_wb1<<<(256 * 128 + 255) / 256, 256, 0, stream>>>(gat1_w, wb1t);
    k_wb2<<<(256 * 1024 + 255) / 256, 256, 0, stream>>>(gat2_w, wb2t);
    k_xcvt<<<(N_NODES * 32 + 255) / 256, 256, 0, stream>>>(x, enc_b2, xf, xb);
    k_wa1<<<1, 128, 0, stream>>>(gat1_w, gat1_asrc, gat1_adst, wa1, wd1);
    k_wa2<<<4, 256, 0, stream>>>(gat2_w, gat2_asrc, gat2_adst, wa2, wd2);

    // ---- NNConv ----
    hipMemsetAsync(agg, 0, 800000 * sizeof(float), stream);
    k_gemT<<<GBT, 256, 0, stream>>>(xf, wtt, T16);
    k_hedge<<<(N_EDGES + 7) / 8, 256, 0, stream>>>(edge_attr, enc_w1, enc_b1, epos2, hEs);
    k_msg2<<<(N_NODES + 7) / 8, 256, 0, stream>>>(rowptr2, cdst, hEs, T16, xb, agg);
    k_h0e<<<(N_NODES + 7) / 8, 256, 0, stream>>>(x, root_w, nn_bias, agg, rowptr,
                                                 wa1, wd1, h0f, esb, edb, mkey);

    // ---- GAT layer 1 ----
    k_mmax<<<(EH + 255) / 256, 256, 0, stream>>>(edge_idx, esb, edb, mkey);
    hipMemsetAsync(den, 0, 100000 * sizeof(float), stream);
    k_watt<<<(EH + 255) / 256, 256, 0, stream>>>(edge_idx, epos, esb, edb, mkey, wv, den);
    k_agg1<<<(N_NODES + 3) / 4, 256, 0, stream>>>(rowptr, csrc, esb, edb, mkey, den, wv, h0f, agg0f);
    k_gemmo<128, __half><<<GBO, 256, 0, stream>>>(agg0f, wb1t, gat1_b, h1f);
    k_esed2<<<N_NODES, 256, 0, stream>>>(h1f, wa2, wd2, esb, edb, mkey);

    // ---- GAT layer 2 ----
    k_mmax<<<(EH + 255) / 256, 256, 0, stream>>>(edge_idx, esb, edb, mkey);
    hipMemsetAsync(den, 0, 100000 * sizeof(float), stream);
    k_watt<<<(EH + 255) / 256, 256, 0, stream>>>(edge_idx, epos, esb, edb, mkey, wv, den);
    k_agg2<<<(N_NODES + 3) / 4, 256, 0, stream>>>(rowptr, csrc, esb, edb, mkey, den, wv, h1f, agg1f);
    k_gemmo<1024, float><<<GBO, 256, 0, stream>>>(agg1f, wb2t, gat2_b, h2);

    // ---- heads ----
    k_wire<<<KWIRE / 4, 256, 0, stream>>>(wire_mask, h2, wire_w, wire_b, out);
    hipMemsetAsync(pooled, 0, (NGRAPH * 256 + NGRAPH) * sizeof(float), stream);
    k_pool<<<(N_NODES + POOL_NB - 1) / POOL_NB, 256, 0, stream>>>(h2, batch, pooled, gcnt);
    k_act<<<NGRAPH * NACT / 4, 256, 0, stream>>>(pooled, gcnt, act_w, act_b, out);
}

// Round 15
// 598.807 us; speedup vs baseline: 1.0072x; 1.0072x over previous
//
#include <hip/hip_runtime.h>
#include <hip/hip_fp16.h>

#define N_NODES 25000
#define M_PAD   25024            // multiple of 16 (1564 tiles)
#define N_TILES 1564
#define N_EDGES 300000
#define IN_DIM  32
#define EDFD    16
#define HIDD    256
#define HEADS   4
#define NACT    16
#define NGRAPH  64
#define KWIRE   1024
#define POOL_NB 64

typedef _Float16 half8v __attribute__((ext_vector_type(8)));
typedef __attribute__((ext_vector_type(4))) float f32x4;

// pin each 32-bit lane of a float4 in a VGPR (opaque to the scheduler -> load must materialize)
__device__ __forceinline__ void pin4(float4& v) {
    asm volatile("" : "+v"(v.x), "+v"(v.y), "+v"(v.z), "+v"(v.w));
}

// ---------------------------------------------------------------- helpers
__device__ __forceinline__ float leaky(float v) { return v > 0.f ? v : 0.2f * v; }
__device__ __forceinline__ int fkey(float f) {
    int b = __float_as_int(f);
    b ^= (b >> 31) & 0x7fffffff;
    return b;
}
__device__ __forceinline__ float funkey(int b) {
    b ^= (b >> 31) & 0x7fffffff;
    return __int_as_float(b);
}

// ---------------------------------------------------------------- CSR build (both directions)
__global__ __launch_bounds__(256) void k_deg2(const int* __restrict__ ei,
                                              int* __restrict__ deg,
                                              int* __restrict__ deg2) {
    int e = blockIdx.x * 256 + threadIdx.x;
    if (e >= N_EDGES) return;
    atomicAdd(&deg[ei[N_EDGES + e]], 1);
    atomicAdd(&deg2[ei[e]], 1);
}

__global__ __launch_bounds__(256) void k_scan2(const int* __restrict__ degA, int* __restrict__ rpA,
                                               const int* __restrict__ degB, int* __restrict__ rpB) {
    const int* deg = blockIdx.x ? degB : degA;
    int* rowptr    = blockIdx.x ? rpB : rpA;
    __shared__ int part[256];
    int t = threadIdx.x;
    const int CH = 98;
    int base = t * CH;
    int s = 0;
    for (int i = 0; i < CH; ++i) {
        int idx = base + i;
        if (idx < N_NODES) s += deg[idx];
    }
    part[t] = s;
    __syncthreads();
    if (t == 0) {
        int run = 0;
        for (int i = 0; i < 256; ++i) { int v = part[i]; part[i] = run; run += v; }
    }
    __syncthreads();
    int run = part[t];
    for (int i = 0; i < CH; ++i) {
        int idx = base + i;
        if (idx < N_NODES) { rowptr[idx] = run; run += deg[idx]; }
    }
    if (N_NODES >= base && N_NODES < base + CH) rowptr[N_NODES] = run;
}

__global__ __launch_bounds__(256) void k_scatter2(const int* __restrict__ ei,
                                                  const int* __restrict__ rowptr,
                                                  const int* __restrict__ rowptr2,
                                                  int* __restrict__ cursor,
                                                  int* __restrict__ cursor2,
                                                  int* __restrict__ csrc,
                                                  int* __restrict__ epos,
                                                  int* __restrict__ cdst,
                                                  int* __restrict__ epos2) {
    int e = blockIdx.x * 256 + threadIdx.x;
    if (e >= N_EDGES) return;
    int src = ei[e], dst = ei[N_EDGES + e];
    int p1 = atomicAdd(&cursor[dst], 1);
    int r1 = rowptr[dst] + p1;
    csrc[r1] = src;
    epos[e] = r1;
    int p2 = atomicAdd(&cursor2[src], 1);
    int r2 = rowptr2[src] + p2;
    cdst[r2] = dst;
    epos2[e] = r2;
}

// ---------------------------------------------------------------- weight prep
__global__ __launch_bounds__(256) void k_w2perm(const float* __restrict__ w2,
                                                __half* __restrict__ Wt) {
    int idx = blockIdx.x * 256 + threadIdx.x;   // co*32 + i
    if (idx >= 32 * 1024) return;
    int co = idx >> 5, i = idx & 31;
    Wt[idx] = __float2half(w2[(co >> 5) * 1024 + i * 32 + (co & 31)]);
}

// head-mean-folded weights: Wb1[d][k], k=h*32+i ; value 0.25*W1[i, h*256+d]
__global__ __launch_bounds__(256) void k_wb1(const float* __restrict__ W1,
                                             __half* __restrict__ Wb) {
    int idx = blockIdx.x * 256 + threadIdx.x;   // d*128+k
    if (idx >= 256 * 128) return;
    int d = idx >> 7, k = idx & 127;
    int h = k >> 5, i = k & 31;
    Wb[idx] = __float2half(0.25f * W1[i * 1024 + h * 256 + d]);
}

// Wb2[d][k], k=h*256+i ; value 0.25*W2[i, h*256+d]
__global__ __launch_bounds__(256) void k_wb2(const float* __restrict__ W2,
                                             __half* __restrict__ Wb) {
    int idx = blockIdx.x * 256 + threadIdx.x;   // d*1024+k
    if (idx >= 256 * 1024) return;
    int d = idx >> 10, k = idx & 1023;
    int h = k >> 8, i = k & 255;
    Wb[idx] = __float2half(0.25f * W2[i * 1024 + h * 256 + d]);
}

__global__ __launch_bounds__(128) void k_wa1(const float* __restrict__ W1,
                                             const float* __restrict__ asrc,
                                             const float* __restrict__ adst,
                                             float* __restrict__ wa,
                                             float* __restrict__ wd) {
    int t = threadIdx.x;            // h*32+i
    int h = t >> 5, i = t & 31;
    float s = 0.f, sd = 0.f;
    for (int d = 0; d < 256; ++d) {
        float w = W1[i * 1024 + h * 256 + d];
        s  += w * asrc[h * 256 + d];
        sd += w * adst[h * 256 + d];
    }
    wa[t] = s; wd[t] = sd;
}

__global__ __launch_bounds__(256) void k_wa2(const float* __restrict__ W2,
                                             const float* __restrict__ asrc,
                                             const float* __restrict__ adst,
                                             float* __restrict__ wa,
                                             float* __restrict__ wd) {
    int idx = blockIdx.x * 256 + threadIdx.x;   // h*256+i
    if (idx >= 1024) return;
    int h = idx >> 8, i = idx & 255;
    float s = 0.f, sd = 0.f;
    for (int d = 0; d < 256; ++d) {
        float w = W2[i * 1024 + h * 256 + d];
        s  += w * asrc[h * 256 + d];
        sd += w * adst[h * 256 + d];
    }
    wa[idx] = s; wd[idx] = sd;
}

__global__ __launch_bounds__(256) void k_xcvt(const float* __restrict__ x,
                                              const float* __restrict__ b2,
                                              __half* __restrict__ xf,
                                              float* __restrict__ xb) {
    int idx = blockIdx.x * 256 + threadIdx.x;
    if (idx >= N_NODES * 32) return;
    int n = idx >> 5, o = idx & 31;
    xf[idx] = __float2half(x[idx]);
    float s = 0.f;
    for (int i = 0; i < 32; ++i) s += x[n * 32 + i] * b2[i * 32 + o];
    xb[idx] = s;
}

// ---------------------------------------------------------------- NNConv
__global__ __launch_bounds__(256) void k_hedge(const float* __restrict__ ea,
                                               const float* __restrict__ w1,
                                               const float* __restrict__ b1,
                                               const int* __restrict__ epos2,
                                               __half* __restrict__ hEs) {
    int t = threadIdx.x;
    int eg = t >> 5, o = t & 31;
    int e = blockIdx.x * 8 + eg;
    if (e >= N_EDGES) return;
    float a = b1[o];
    for (int k = 0; k < EDFD; ++k) a += ea[e * EDFD + k] * w1[k * 32 + o];
    hEs[(size_t)epos2[e] * 32 + o] = __float2half(fmaxf(a, 0.f));
}

__global__ __launch_bounds__(256) void k_msg2(const int* __restrict__ rowptr2,
                                              const int* __restrict__ cdst,
                                              const __half* __restrict__ hEs,
                                              const __half* __restrict__ T,
                                              const float* __restrict__ xb,
                                              float* __restrict__ agg) {
    int g = threadIdx.x >> 5, o = threadIdx.x & 31;
    int src = blockIdx.x * 8 + g;
    if (src >= N_NODES) return;
    int r0 = rowptr2[src], r1 = rowptr2[src + 1];
    if (r0 == r1) return;
    float tcol[32];
    const __half* Tp = T + (size_t)src * 1024 + o;
    #pragma unroll
    for (int j = 0; j < 32; ++j) tcol[j] = __half2float(Tp[j * 32]);
    float xbv = xb[src * 32 + o];
    for (int r = r0; r < r1; ++r) {
        int dst = cdst[r];
        const __half2* hp2 = (const __half2*)(hEs + (size_t)r * 32);
        float m = xbv;
        #pragma unroll
        for (int jj = 0; jj < 16; ++jj) {
            float2 hv = __half22float2(hp2[jj]);
            m += hv.x * tcol[2 * jj] + hv.y * tcol[2 * jj + 1];
        }
        atomicAdd(&agg[dst * 32 + o], m);
    }
}

// h0 = relu(agg/deg + x@root_w + bias) -> fp16, fused layer1 es/ed/mkey
__global__ __launch_bounds__(256) void k_h0e(const float* __restrict__ x,
                                             const float* __restrict__ root_w,
                                             const float* __restrict__ nn_bias,
                                             const float* __restrict__ agg,
                                             const int* __restrict__ rowptr,
                                             const float* __restrict__ wa,
                                             const float* __restrict__ wd,
                                             __half* __restrict__ h0f,
                                             float* __restrict__ es,
                                             float* __restrict__ ed,
                                             int* __restrict__ mkey) {
    int t = threadIdx.x;
    int ng = t >> 5, o = t & 31;
    int n = blockIdx.x * 8 + ng;
    if (n >= N_NODES) return;
    float s = nn_bias[o];
    for (int k = 0; k < IN_DIM; ++k) s += x[n * IN_DIM + k] * root_w[k * 32 + o];
    float c = fmaxf((float)(rowptr[n + 1] - rowptr[n]), 1.f);
    s += agg[n * IN_DIM + o] / c;
    float v = fmaxf(s, 0.f);
    h0f[n * IN_DIM + o] = __float2half(v);
    #pragma unroll
    for (int h = 0; h < 4; ++h) {
        float ss = v * wa[h * 32 + o];
        float dd = v * wd[h * 32 + o];
        #pragma unroll
        for (int off = 16; off; off >>= 1) {
            ss += __shfl_down(ss, off, 32);
            dd += __shfl_down(dd, off, 32);
        }
        if (o == 0) {
            es[n * 4 + h] = ss; ed[n * 4 + h] = dd;
            mkey[n * 4 + h] = fkey(leaky(ss + dd));
        }
    }
}

// ---------------------------------------------------------------- GEMM 1: T = xf @ wtt^T, out [M,1024] fp16
__global__ __launch_bounds__(256, 2) void k_gemT(const __half* __restrict__ A,
                                                 const __half* __restrict__ Wt,
                                                 __half* __restrict__ C) {
    __shared__ __half cst[4][16 * 36];
    int t = threadIdx.x, wid = t >> 6, lane = t & 63;
    int lr = lane & 15, lk = (lane >> 4) * 8;

    int bid = blockIdx.x;
    int xcd = bid & 7, j = bid >> 3;
    int sx = j & 31;
    int y = ((j >> 5) << 3) | xcd;            // 0..103
    int n0 = sx * 32;

    half8v bfr[2];
    #pragma unroll
    for (int c = 0; c < 2; ++c) {
        float4 raw = *(const float4*)(Wt + (size_t)(n0 + c * 16 + lr) * 32 + lk);
        pin4(raw);
        bfr[c] = __builtin_bit_cast(half8v, raw);
    }

    int tb = (y * 4 + wid) * 4;
    for (int pp = 0; pp < 4; pp += 2) {
        int tA = tb + pp;
        if (tA >= N_TILES) break;
        int mA = tA * 16, mB = mA + 16;
        half8v aA = *(const half8v*)(A + (size_t)(mA + lr) * 32 + lk);
        half8v aB = *(const half8v*)(A + (size_t)(mB + lr) * 32 + lk);
        f32x4 acc[2][2];
        #pragma unroll
        for (int i = 0; i < 2; ++i)
            #pragma unroll
            for (int c = 0; c < 2; ++c)
                acc[i][c] = (f32x4){0.f, 0.f, 0.f, 0.f};
        acc[0][0] = __builtin_amdgcn_mfma_f32_16x16x32_f16(aA, bfr[0], acc[0][0], 0, 0, 0);
        acc[0][1] = __builtin_amdgcn_mfma_f32_16x16x32_f16(aA, bfr[1], acc[0][1], 0, 0, 0);
        acc[1][0] = __builtin_amdgcn_mfma_f32_16x16x32_f16(aB, bfr[0], acc[1][0], 0, 0, 0);
        acc[1][1] = __builtin_amdgcn_mfma_f32_16x16x32_f16(aB, bfr[1], acc[1][1], 0, 0, 0);

        int rbase = (lane >> 4) * 4;
        #pragma unroll
        for (int ti = 0; ti < 2; ++ti) {
            #pragma unroll
            for (int c = 0; c < 2; ++c)
                #pragma unroll
                for (int r = 0; r < 4; ++r)
                    cst[wid][(rbase + r) * 36 + c * 16 + lr] = __float2half(acc[ti][c][r]);
            int m0 = ti ? mB : mA;
            #pragma unroll
            for (int p = 0; p < 2; ++p) {
                int row = p * 8 + (lane >> 3), hb = lane & 7;
                float2 v = *(const float2*)((const char*)&cst[wid][0] + row * 72 + hb * 8);
                *(float2*)((char*)C + ((size_t)(m0 + row) * 1024 + n0) * 2 + hb * 8) = v;
            }
        }
    }
}

// ---------------------------------------------------------------- GEMM 2: head-mean-folded, out [M,256]
// C = relu(A[M,K] @ Wt[256,K]^T + bias). OT = __half (h1) or float (h2). K in {128,1024}.
// XCD-grouped decode: bid = xcd + 8*(strip + 8*yhi); all 8 strips of a row-group share one XCD.
template <int K, typename OT>
__global__ __launch_bounds__(256, 2) void k_gemmo(const __half* __restrict__ A,
                                                  const __half* __restrict__ Wt,
                                                  const float* __restrict__ bias,
                                                  OT* __restrict__ C) {
    constexpr int KC  = (K > 256) ? 4 : 1;      // chunks
    constexpr int CK  = K / KC;                 // cols per chunk
    constexpr int KSC = CK / 32;
    __shared__ float cst[4][16 * 36];
    int t = threadIdx.x, wid = t >> 6, lane = t & 63;
    int lr = lane & 15, lk = (lane >> 4) * 8;

    int bid = blockIdx.x;
    int xcd = bid & 7, rest = bid >> 3;
    int strip = rest & 7, yhi = rest >> 3;
    int y = yhi * 8 + xcd;                      // row-group; same y -> same XCD
    if (y >= 98) return;
    int n0 = strip * 32;
    float bv0 = bias[n0 + lr], bv1 = bias[n0 + 16 + lr];

    int tb = (y * 4 + wid) * 4;
    for (int pp = 0; pp < 4; pp += 2) {
        int tA = tb + pp;
        if (tA >= N_TILES) break;
        int mA = tA * 16, mB = mA + 16;
        f32x4 acc[2][2];
        #pragma unroll
        for (int i = 0; i < 2; ++i)
            #pragma unroll
            for (int c = 0; c < 2; ++c)
                acc[i][c] = (f32x4){0.f, 0.f, 0.f, 0.f};

        for (int kc = 0; kc < KC; ++kc) {
            half8v bfr[KSC][2];
            #pragma unroll
            for (int ks = 0; ks < KSC; ++ks)
                #pragma unroll
                for (int c = 0; c < 2; ++c) {
                    float4 raw = *(const float4*)(Wt + (size_t)(n0 + c * 16 + lr) * K + kc * CK + ks * 32 + lk);
                    pin4(raw);
                    bfr[ks][c] = __builtin_bit_cast(half8v, raw);
                }
            const __half* pA = A + (size_t)(mA + lr) * K + kc * CK + lk;
            const __half* pB = A + (size_t)(mB + lr) * K + kc * CK + lk;
            #pragma unroll
            for (int ks = 0; ks < KSC; ++ks) {
                half8v aA = *(const half8v*)(pA + (size_t)ks * 32);
                half8v aB = *(const half8v*)(pB + (size_t)ks * 32);
                acc[0][0] = __builtin_amdgcn_mfma_f32_16x16x32_f16(aA, bfr[ks][0], acc[0][0], 0, 0, 0);
                acc[0][1] = __builtin_amdgcn_mfma_f32_16x16x32_f16(aA, bfr[ks][1], acc[0][1], 0, 0, 0);
                acc[1][0] = __builtin_amdgcn_mfma_f32_16x16x32_f16(aB, bfr[ks][0], acc[1][0], 0, 0, 0);
                acc[1][1] = __builtin_amdgcn_mfma_f32_16x16x32_f16(aB, bfr[ks][1], acc[1][1], 0, 0, 0);
            }
        }

        int rbase = (lane >> 4) * 4;
        #pragma unroll
        for (int ti = 0; ti < 2; ++ti) {
            #pragma unroll
            for (int c = 0; c < 2; ++c)
                #pragma unroll
                for (int r = 0; r < 4; ++r)
                    cst[wid][(rbase + r) * 36 + c * 16 + lr] =
                        fmaxf(acc[ti][c][r] + (c ? bv1 : bv0), 0.f);
            int m0 = ti ? mB : mA;
            int row = lane >> 2, cg = lane & 3;   // 16 rows x 4 col-groups of 8
            const float* sp = &cst[wid][row * 36 + cg * 8];
            if constexpr (sizeof(OT) == 2) {
                __half2 o0 = __float22half2_rn(make_float2(sp[0], sp[1]));
                __half2 o1 = __float22half2_rn(make_float2(sp[2], sp[3]));
                __half2 o2 = __float22half2_rn(make_float2(sp[4], sp[5]));
                __half2 o3 = __float22half2_rn(make_float2(sp[6], sp[7]));
                float4 v = make_float4(__uint_as_float(*(unsigned*)&o0), __uint_as_float(*(unsigned*)&o1),
                                       __uint_as_float(*(unsigned*)&o2), __uint_as_float(*(unsigned*)&o3));
                *(float4*)((__half*)C + (size_t)(m0 + row) * 256 + n0 + cg * 8) = v;
            } else {
                float4 v0 = make_float4(sp[0], sp[1], sp[2], sp[3]);
                float4 v1 = make_float4(sp[4], sp[5], sp[6], sp[7]);
                float* cp = (float*)C + (size_t)(m0 + row) * 256 + n0 + cg * 8;
                *(float4*)cp = v0;
                *(float4*)(cp + 4) = v1;
            }
        }
    }
}

// ---------------------------------------------------------------- attention scalars
__global__ __launch_bounds__(256) void k_esed2(const __half* __restrict__ h1f,
                                               const float* __restrict__ wa,
                                               const float* __restrict__ wd,
                                               float* __restrict__ es,
                                               float* __restrict__ ed,
                                               int* __restrict__ mkey) {
    int n = blockIdx.x;
    int h = threadIdx.x >> 6, lane = threadIdx.x & 63;
    float s = 0.f, d2 = 0.f;
    for (int d = lane; d < 256; d += 64) {
        float v = __half2float(h1f[(size_t)n * 256 + d]);
        s  += v * wa[h * 256 + d];
        d2 += v * wd[h * 256 + d];
    }
    #pragma unroll
    for (int off = 32; off; off >>= 1) {
        s  += __shfl_down(s, off);
        d2 += __shfl_down(d2, off);
    }
    if (lane == 0) {
        es[n * 4 + h] = s; ed[n * 4 + h] = d2;
        mkey[n * 4 + h] = fkey(leaky(s + d2));
    }
}

__global__ __launch_bounds__(256) void k_mmax(const int* __restrict__ ei,
                                              const float* __restrict__ es,
                                              const float* __restrict__ ed,
                                              int* __restrict__ mkey) {
    int idx = blockIdx.x * 256 + threadIdx.x;
    if (idx >= N_EDGES * 4) return;
    int e = idx >> 2, h = idx & 3;
    int src = ei[e], dst = ei[N_EDGES + e];
    atomicMax(&mkey[dst * 4 + h], fkey(leaky(es[src * 4 + h] + ed[dst * 4 + h])));
}

__global__ __launch_bounds__(256) void k_watt(const int* __restrict__ ei,
                                              const int* __restrict__ epos,
                                              const float* __restrict__ es,
                                              const float* __restrict__ ed,
                                              const int* __restrict__ mkey,
                                              float* __restrict__ wv,
                                              float* __restrict__ den) {
    int idx = blockIdx.x * 256 + threadIdx.x;
    if (idx >= N_EDGES * 4) return;
    int e = idx >> 2, h = idx & 3;
    int src = ei[e], dst = ei[N_EDGES + e];
    float v = leaky(es[src * 4 + h] + ed[dst * 4 + h]);
    float w = __expf(v - funkey(mkey[dst * 4 + h]));
    wv[(size_t)epos[e] * 4 + h] = w;
    atomicAdd(&den[dst * 4 + h], w);
}

// ---------------------------------------------------------------- pre-GEMM aggregation
__global__ __launch_bounds__(256) void k_agg1(const int* __restrict__ rowptr,
                                              const int* __restrict__ csrc,
                                              const float* __restrict__ es,
                                              const float* __restrict__ ed,
                                              const int* __restrict__ mkey,
                                              const float* __restrict__ denb,
                                              const float* __restrict__ wv,
                                              const __half* __restrict__ h0f,
                                              __half* __restrict__ agg0) {
    int dst = blockIdx.x * 4 + (threadIdx.x >> 6);
    if (dst >= N_NODES) return;
    int lane = threadIdx.x & 63;
    int h = lane >> 4, i2 = lane & 15;
    float m = funkey(mkey[dst * 4 + h]);
    float vself = leaky(es[dst * 4 + h] + ed[dst * 4 + h]);
    float ws = __expf(vself - m);
    float dn = denb[dst * 4 + h] + ws;
    int r0 = rowptr[dst], r1 = rowptr[dst + 1];

    __half2 hv = *(const __half2*)(h0f + (size_t)dst * 32 + i2 * 2);
    float2 f = __half22float2(hv);
    float ax = ws * f.x, ay = ws * f.y;
    for (int r = r0; r < r1; ++r) {
        int src = csrc[r];
        float w = wv[(size_t)r * 4 + h];
        __half2 sv = *(const __half2*)(h0f + (size_t)src * 32 + i2 * 2);
        float2 g = __half22float2(sv);
        ax += w * g.x; ay += w * g.y;
    }
    float inv = 1.f / (dn + 1e-16f);
    *(__half2*)(agg0 + (size_t)dst * 128 + h * 32 + i2 * 2) =
        __float22half2_rn(make_float2(ax * inv, ay * inv));
}

__global__ __launch_bounds__(256) void k_agg2(const int* __restrict__ rowptr,
                                              const int* __restrict__ csrc,
                                              const float* __restrict__ es,
                                              const float* __restrict__ ed,
                                              const int* __restrict__ mkey,
                                              const float* __restrict__ denb,
                                              const float* __restrict__ wv,
                                              const __half* __restrict__ h1f,
                                              __half* __restrict__ agg1) {
    int dst = blockIdx.x * 4 + (threadIdx.x >> 6);
    if (dst >= N_NODES) return;
    int lane = threadIdx.x & 63;
    float ws[4], dn[4];
    #pragma unroll
    for (int h = 0; h < 4; ++h) {
        float m = funkey(mkey[dst * 4 + h]);
        float vself = leaky(es[dst * 4 + h] + ed[dst * 4 + h]);
        ws[h] = __expf(vself - m);
        dn[h] = denb[dst * 4 + h] + ws[h];
    }
    int r0 = rowptr[dst], r1 = rowptr[dst + 1];

    float acc[4][4];
    {
        float2 q = *(const float2*)(h1f + (size_t)dst * 256 + lane * 4);
        const __half2* hq = (const __half2*)&q;
        float2 f0 = __half22float2(hq[0]), f1 = __half22float2(hq[1]);
        #pragma unroll
        for (int h = 0; h < 4; ++h) {
            acc[h][0] = ws[h] * f0.x; acc[h][1] = ws[h] * f0.y;
            acc[h][2] = ws[h] * f1.x; acc[h][3] = ws[h] * f1.y;
        }
    }
    for (int r = r0; r < r1; ++r) {
        int src = csrc[r];
        float4 w4 = *(const float4*)(wv + (size_t)r * 4);
        float2 q = *(const float2*)(h1f + (size_t)src * 256 + lane * 4);
        const __half2* hq = (const __half2*)&q;
        float2 f0 = __half22float2(hq[0]), f1 = __half22float2(hq[1]);
        acc[0][0] += w4.x * f0.x; acc[0][1] += w4.x * f0.y; acc[0][2] += w4.x * f1.x; acc[0][3] += w4.x * f1.y;
        acc[1][0] += w4.y * f0.x; acc[1][1] += w4.y * f0.y; acc[1][2] += w4.y * f1.x; acc[1][3] += w4.y * f1.y;
        acc[2][0] += w4.z * f0.x; acc[2][1] += w4.z * f0.y; acc[2][2] += w4.z * f1.x; acc[2][3] += w4.z * f1.y;
        acc[3][0] += w4.w * f0.x; acc[3][1] += w4.w * f0.y; acc[3][2] += w4.w * f1.x; acc[3][3] += w4.w * f1.y;
    }
    #pragma unroll
    for (int h = 0; h < 4; ++h) {
        float inv = 1.f / (dn[h] + 1e-16f);
        __half2 o0 = __float22half2_rn(make_float2(acc[h][0] * inv, acc[h][1] * inv));
        __half2 o1 = __float22half2_rn(make_float2(acc[h][2] * inv, acc[h][3] * inv));
        __half2* op = (__half2*)(agg1 + (size_t)dst * 1024 + h * 256 + lane * 4);
        op[0] = o0; op[1] = o1;
    }
}

// ---------------------------------------------------------------- heads
__global__ __launch_bounds__(256) void k_wire(const int* __restrict__ wm,
                                              const float* __restrict__ h2,
                                              const float* __restrict__ ww,
                                              const float* __restrict__ wb,
                                              float* __restrict__ out) {
    int k = blockIdx.x * 4 + (threadIdx.x >> 6);
    int lane = threadIdx.x & 63;
    if (k >= KWIRE) return;
    int n = wm[k];
    float s = 0.f;
    for (int d = lane; d < 256; d += 64) s += h2[(size_t)n * 256 + d] * ww[d];
    #pragma unroll
    for (int off = 32; off; off >>= 1) s += __shfl_down(s, off);
    if (lane == 0) out[k] = s + wb[0];
}

__global__ __launch_bounds__(256) void k_pool(const float* __restrict__ h2,
                                              const int* __restrict__ batch,
                                              float* __restrict__ pooled,
                                              float* __restrict__ gcnt) {
    int n0 = blockIdx.x * POOL_NB;
    int n1 = n0 + POOL_NB; if (n1 > N_NODES) n1 = N_NODES;
    int d = threadIdx.x;
    int cur = batch[n0];
    float acc = 0.f, cnt = 0.f;
    for (int n = n0; n < n1; ++n) {
        int g = batch[n];
        if (g != cur) {
            atomicAdd(&pooled[cur * 256 + d], acc);
            if (d == 0) atomicAdd(&gcnt[cur], cnt);
            acc = 0.f; cnt = 0.f; cur = g;
        }
        acc += h2[(size_t)n * 256 + d];
        cnt += 1.f;
    }
    atomicAdd(&pooled[cur * 256 + d], acc);
    if (d == 0) atomicAdd(&gcnt[cur], cnt);
}

__global__ __launch_bounds__(256) void k_act(const float* __restrict__ pooled,
                                             const float* __restrict__ gcnt,
                                             const float* __restrict__ aw,
                                             const float* __restrict__ ab,
                                             float* __restrict__ out) {
    int u = blockIdx.x * 4 + (threadIdx.x >> 6);
    int lane = threadIdx.x & 63;
    if (u >= NGRAPH * NACT) return;
    int g = u >> 4, a = u & 15;
    float c = fmaxf(gcnt[g], 1.f);
    float s = 0.f;
    for (int d = lane; d < 256; d += 64) s += pooled[g * 256 + d] * aw[d * 16 + a];
    #pragma unroll
    for (int off = 32; off; off >>= 1) s += __shfl_down(s, off);
    if (lane == 0) out[KWIRE + u] = s / c + ab[a];
}

// ---------------------------------------------------------------- launch
extern "C" void kernel_launch(void* const* d_in, const int* in_sizes, int n_in,
                              void* d_out, int out_size, void* d_ws, size_t ws_size,
                              hipStream_t stream) {
    const float* x        = (const float*)d_in[0];
    const float* edge_attr= (const float*)d_in[1];
    const int*   wire_mask= (const int*)d_in[2];
    const int*   edge_idx = (const int*)d_in[3];
    const int*   batch    = (const int*)d_in[4];
    const float* enc_w1   = (const float*)d_in[5];
    const float* enc_b1   = (const float*)d_in[6];
    const float* enc_w2   = (const float*)d_in[7];
    const float* enc_b2   = (const float*)d_in[8];
    const float* root_w   = (const float*)d_in[9];
    const float* nn_bias  = (const float*)d_in[10];
    const float* gat1_w   = (const float*)d_in[11];
    const float* gat1_asrc= (const float*)d_in[12];
    const float* gat1_adst= (const float*)d_in[13];
    const float* gat1_b   = (const float*)d_in[14];
    const float* gat2_w   = (const float*)d_in[15];
    const float* gat2_asrc= (const float*)d_in[16];
    const float* gat2_adst= (const float*)d_in[17];
    const float* gat2_b   = (const float*)d_in[18];
    const float* wire_w   = (const float*)d_in[19];
    const float* wire_b   = (const float*)d_in[20];
    const float* act_w    = (const float*)d_in[21];
    const float* act_b    = (const float*)d_in[22];
    float* out = (float*)d_out;

    float* ws = (float*)d_ws;
    size_t off = 0;
    __half* T16   = (__half*)(ws + off); off += (size_t)M_PAD * 1024 / 2;
    __half* agg1f = (__half*)(ws + off); off += (size_t)M_PAD * 1024 / 2;
    __half* agg0f = (__half*)(ws + off); off += (size_t)M_PAD * 128 / 2;
    __half* h0f   = (__half*)(ws + off); off += (size_t)M_PAD * 32 / 2;
    __half* h1f   = (__half*)(ws + off); off += (size_t)M_PAD * 256 / 2;
    __half* xf    = (__half*)(ws + off); off += (size_t)M_PAD * 32 / 2;
    __half* hEs   = (__half*)(ws + off); off += (size_t)N_EDGES * 32 / 2;
    float* xb     = ws + off; off += 800000;
    float* agg    = ws + off; off += 800000;
    float* esb    = ws + off; off += 100000;
    float* edb    = ws + off; off += 100000;
    float* h2     = ws + off; off += (size_t)M_PAD * 256;
    float* pooled = ws + off; off += NGRAPH * 256;
    float* gcnt   = ws + off; off += NGRAPH;
    int* deg      = (int*)(ws + off); off += 25600;   // zero-region start
    int* deg2     = (int*)(ws + off); off += 25600;
    int* cursor   = (int*)(ws + off); off += 25600;
    int* cursor2  = (int*)(ws + off); off += 25600;   // zero-region end
    int* rowptr   = (int*)(ws + off); off += 25600;
    int* rowptr2  = (int*)(ws + off); off += 25600;
    int* csrc     = (int*)(ws + off); off += N_EDGES;
    int* epos     = (int*)(ws + off); off += N_EDGES;
    int* cdst     = (int*)(ws + off); off += N_EDGES;
    int* epos2    = (int*)(ws + off); off += N_EDGES;
    int* mkey     = (int*)(ws + off); off += 100000;
    float* den    = ws + off; off += 100000;
    float* wv     = ws + off; off += (size_t)N_EDGES * 4;
    __half* wtt   = (__half*)(ws + off); off += 16384;    // enc_w2 perm [1024][32]
    __half* wb1t  = (__half*)(ws + off); off += 16384;    // [256][128]
    __half* wb2t  = (__half*)(ws + off); off += 131072;   // [256][1024]
    float* wa1    = ws + off; off += 128;
    float* wd1    = ws + off; off += 128;
    float* wa2    = ws + off; off += 1024;
    float* wd2    = ws + off; off += 1024;

    const int EH = N_EDGES * 4;
    const int GBT = 3328;   // T-gemm: 8 xcd x 13 ygroups x 32 strips
    const int GBO2 = 832;   // out-256 gemms: 8 xcd x 13 yhi x 8 strips (y>=98 idle)

    // ---- CSR build ----
    hipMemsetAsync(deg, 0, 4 * 25600 * sizeof(int), stream);
    k_deg2<<<(N_EDGES + 255) / 256, 256, 0, stream>>>(edge_idx, deg, deg2);
    k_scan2<<<2, 256, 0, stream>>>(deg, rowptr, deg2, rowptr2);
    k_scatter2<<<(N_EDGES + 255) / 256, 256, 0, stream>>>(edge_idx, rowptr, rowptr2,
                                                          cursor, cursor2, csrc, epos, cdst, epos2);

    // ---- weight prep ----
    k_w2perm<<<(32 * 1024 + 255) / 256, 256, 0, stream>>>(enc_w2, wtt);
    k_wb1<<<(256 * 128 + 255) / 256, 256, 0, stream>>>(gat1_w, wb1t);
    k_wb2<<<(256 * 1024 + 255) / 256, 256, 0, stream>>>(gat2_w, wb2t);
    k_xcvt<<<(N_NODES * 32 + 255) / 256, 256, 0, stream>>>(x, enc_b2, xf, xb);
    k_wa1<<<1, 128, 0, stream>>>(gat1_w, gat1_asrc, gat1_adst, wa1, wd1);
    k_wa2<<<4, 256, 0, stream>>>(gat2_w, gat2_asrc, gat2_adst, wa2, wd2);

    // ---- NNConv ----
    hipMemsetAsync(agg, 0, 800000 * sizeof(float), stream);
    k_gemT<<<GBT, 256, 0, stream>>>(xf, wtt, T16);
    k_hedge<<<(N_EDGES + 7) / 8, 256, 0, stream>>>(edge_attr, enc_w1, enc_b1, epos2, hEs);
    k_msg2<<<(N_NODES + 7) / 8, 256, 0, stream>>>(rowptr2, cdst, hEs, T16, xb, agg);
    k_h0e<<<(N_NODES + 7) / 8, 256, 0, stream>>>(x, root_w, nn_bias, agg, rowptr,
                                                 wa1, wd1, h0f, esb, edb, mkey);

    // ---- GAT layer 1 ----
    k_mmax<<<(EH + 255) / 256, 256, 0, stream>>>(edge_idx, esb, edb, mkey);
    hipMemsetAsync(den, 0, 100000 * sizeof(float), stream);
    k_watt<<<(EH + 255) / 256, 256, 0, stream>>>(edge_idx, epos, esb, edb, mkey, wv, den);
    k_agg1<<<(N_NODES + 3) / 4, 256, 0, stream>>>(rowptr, csrc, esb, edb, mkey, den, wv, h0f, agg0f);
    k_gemmo<128, __half><<<GBO2, 256, 0, stream>>>(agg0f, wb1t, gat1_b, h1f);
    k_esed2<<<N_NODES, 256, 0, stream>>>(h1f, wa2, wd2, esb, edb, mkey);

    // ---- GAT layer 2 ----
    k_mmax<<<(EH + 255) / 256, 256, 0, stream>>>(edge_idx, esb, edb, mkey);
    hipMemsetAsync(den, 0, 100000 * sizeof(float), stream);
    k_watt<<<(EH + 255) / 256, 256, 0, stream>>>(edge_idx, epos, esb, edb, mkey, wv, den);
    k_agg2<<<(N_NODES + 3) / 4, 256, 0, stream>>>(rowptr, csrc, esb, edb, mkey, den, wv, h1f, agg1f);
    k_gemmo<1024, float><<<GBO2, 256, 0, stream>>>(agg1f, wb2t, gat2_b, h2);

    // ---- heads ----
    k_wire<<<KWIRE / 4, 256, 0, stream>>>(wire_mask, h2, wire_w, wire_b, out);
    hipMemsetAsync(pooled, 0, (NGRAPH * 256 + NGRAPH) * sizeof(float), stream);
    k_pool<<<(N_NODES + POOL_NB - 1) / POOL_NB, 256, 0, stream>>>(h2, batch, pooled, gcnt);
    k_act<<<NGRAPH * NACT / 4, 256, 0, stream>>>(pooled, gcnt, act_w, act_b, out);
}

// Round 16
// 583.399 us; speedup vs baseline: 1.0338x; 1.0264x over previous
//
#include <hip/hip_runtime.h>
#include <hip/hip_fp16.h>

#define N_NODES 25000
#define M_PAD   25024            // multiple of 16 (1564 tiles)
#define N_TILES 1564
#define N_PAIRS 782
#define N_EDGES 300000
#define IN_DIM  32
#define EDFD    16
#define HIDD    256
#define HEADS   4
#define NACT    16
#define NGRAPH  64
#define KWIRE   1024
#define POOL_NB 64

typedef _Float16 half8v __attribute__((ext_vector_type(8)));
typedef __attribute__((ext_vector_type(4))) float f32x4;

// pin each 32-bit lane of a float4 in a VGPR (load must materialize; no remat/refetch)
__device__ __forceinline__ void pin4(float4& v) {
    asm volatile("" : "+v"(v.x), "+v"(v.y), "+v"(v.z), "+v"(v.w));
}

// ---------------------------------------------------------------- helpers
__device__ __forceinline__ float leaky(float v) { return v > 0.f ? v : 0.2f * v; }
__device__ __forceinline__ int fkey(float f) {
    int b = __float_as_int(f);
    b ^= (b >> 31) & 0x7fffffff;
    return b;
}
__device__ __forceinline__ float funkey(int b) {
    b ^= (b >> 31) & 0x7fffffff;
    return __int_as_float(b);
}

// ---------------------------------------------------------------- CSR build (both directions)
__global__ __launch_bounds__(256) void k_deg2(const int* __restrict__ ei,
                                              int* __restrict__ deg,
                                              int* __restrict__ deg2) {
    int e = blockIdx.x * 256 + threadIdx.x;
    if (e >= N_EDGES) return;
    atomicAdd(&deg[ei[N_EDGES + e]], 1);
    atomicAdd(&deg2[ei[e]], 1);
}

__global__ __launch_bounds__(256) void k_scan2(const int* __restrict__ degA, int* __restrict__ rpA,
                                               const int* __restrict__ degB, int* __restrict__ rpB) {
    const int* deg = blockIdx.x ? degB : degA;
    int* rowptr    = blockIdx.x ? rpB : rpA;
    __shared__ int part[256];
    int t = threadIdx.x;
    const int CH = 98;
    int base = t * CH;
    int s = 0;
    for (int i = 0; i < CH; ++i) {
        int idx = base + i;
        if (idx < N_NODES) s += deg[idx];
    }
    part[t] = s;
    __syncthreads();
    if (t == 0) {
        int run = 0;
        for (int i = 0; i < 256; ++i) { int v = part[i]; part[i] = run; run += v; }
    }
    __syncthreads();
    int run = part[t];
    for (int i = 0; i < CH; ++i) {
        int idx = base + i;
        if (idx < N_NODES) { rowptr[idx] = run; run += deg[idx]; }
    }
    if (N_NODES >= base && N_NODES < base + CH) rowptr[N_NODES] = run;
}

__global__ __launch_bounds__(256) void k_scatter2(const int* __restrict__ ei,
                                                  const int* __restrict__ rowptr,
                                                  const int* __restrict__ rowptr2,
                                                  int* __restrict__ cursor,
                                                  int* __restrict__ cursor2,
                                                  int* __restrict__ csrc,
                                                  int* __restrict__ epos,
                                                  int* __restrict__ cdst,
                                                  int* __restrict__ epos2) {
    int e = blockIdx.x * 256 + threadIdx.x;
    if (e >= N_EDGES) return;
    int src = ei[e], dst = ei[N_EDGES + e];
    int p1 = atomicAdd(&cursor[dst], 1);
    int r1 = rowptr[dst] + p1;
    csrc[r1] = src;
    epos[e] = r1;
    int p2 = atomicAdd(&cursor2[src], 1);
    int r2 = rowptr2[src] + p2;
    cdst[r2] = dst;
    epos2[e] = r2;
}

// ---------------------------------------------------------------- weight prep
__global__ __launch_bounds__(256) void k_w2perm(const float* __restrict__ w2,
                                                __half* __restrict__ Wt) {
    int idx = blockIdx.x * 256 + threadIdx.x;   // co*32 + i
    if (idx >= 32 * 1024) return;
    int co = idx >> 5, i = idx & 31;
    Wt[idx] = __float2half(w2[(co >> 5) * 1024 + i * 32 + (co & 31)]);
}

// head-mean-folded weights: Wb1[d][k], k=h*32+i ; value 0.25*W1[i, h*256+d]
__global__ __launch_bounds__(256) void k_wb1(const float* __restrict__ W1,
                                             __half* __restrict__ Wb) {
    int idx = blockIdx.x * 256 + threadIdx.x;   // d*128+k
    if (idx >= 256 * 128) return;
    int d = idx >> 7, k = idx & 127;
    int h = k >> 5, i = k & 31;
    Wb[idx] = __float2half(0.25f * W1[i * 1024 + h * 256 + d]);
}

// Wb2[d][k], k=h*256+i ; value 0.25*W2[i, h*256+d]
__global__ __launch_bounds__(256) void k_wb2(const float* __restrict__ W2,
                                             __half* __restrict__ Wb) {
    int idx = blockIdx.x * 256 + threadIdx.x;   // d*1024+k
    if (idx >= 256 * 1024) return;
    int d = idx >> 10, k = idx & 1023;
    int h = k >> 8, i = k & 255;
    Wb[idx] = __float2half(0.25f * W2[i * 1024 + h * 256 + d]);
}

__global__ __launch_bounds__(128) void k_wa1(const float* __restrict__ W1,
                                             const float* __restrict__ asrc,
                                             const float* __restrict__ adst,
                                             float* __restrict__ wa,
                                             float* __restrict__ wd) {
    int t = threadIdx.x;            // h*32+i
    int h = t >> 5, i = t & 31;
    float s = 0.f, sd = 0.f;
    for (int d = 0; d < 256; ++d) {
        float w = W1[i * 1024 + h * 256 + d];
        s  += w * asrc[h * 256 + d];
        sd += w * adst[h * 256 + d];
    }
    wa[t] = s; wd[t] = sd;
}

__global__ __launch_bounds__(256) void k_wa2(const float* __restrict__ W2,
                                             const float* __restrict__ asrc,
                                             const float* __restrict__ adst,
                                             float* __restrict__ wa,
                                             float* __restrict__ wd) {
    int idx = blockIdx.x * 256 + threadIdx.x;   // h*256+i
    if (idx >= 1024) return;
    int h = idx >> 8, i = idx & 255;
    float s = 0.f, sd = 0.f;
    for (int d = 0; d < 256; ++d) {
        float w = W2[i * 1024 + h * 256 + d];
        s  += w * asrc[h * 256 + d];
        sd += w * adst[h * 256 + d];
    }
    wa[idx] = s; wd[idx] = sd;
}

__global__ __launch_bounds__(256) void k_xcvt(const float* __restrict__ x,
                                              const float* __restrict__ b2,
                                              __half* __restrict__ xf,
                                              float* __restrict__ xb) {
    int idx = blockIdx.x * 256 + threadIdx.x;
    if (idx >= N_NODES * 32) return;
    int n = idx >> 5, o = idx & 31;
    xf[idx] = __float2half(x[idx]);
    float s = 0.f;
    for (int i = 0; i < 32; ++i) s += x[n * 32 + i] * b2[i * 32 + o];
    xb[idx] = s;
}

// ---------------------------------------------------------------- NNConv
__global__ __launch_bounds__(256) void k_hedge(const float* __restrict__ ea,
                                               const float* __restrict__ w1,
                                               const float* __restrict__ b1,
                                               const int* __restrict__ epos2,
                                               __half* __restrict__ hEs) {
    int t = threadIdx.x;
    int eg = t >> 5, o = t & 31;
    int e = blockIdx.x * 8 + eg;
    if (e >= N_EDGES) return;
    float a = b1[o];
    for (int k = 0; k < EDFD; ++k) a += ea[e * EDFD + k] * w1[k * 32 + o];
    hEs[(size_t)epos2[e] * 32 + o] = __float2half(fmaxf(a, 0.f));
}

__global__ __launch_bounds__(256) void k_msg2(const int* __restrict__ rowptr2,
                                              const int* __restrict__ cdst,
                                              const __half* __restrict__ hEs,
                                              const __half* __restrict__ T,
                                              const float* __restrict__ xb,
                                              float* __restrict__ agg) {
    int g = threadIdx.x >> 5, o = threadIdx.x & 31;
    int src = blockIdx.x * 8 + g;
    if (src >= N_NODES) return;
    int r0 = rowptr2[src], r1 = rowptr2[src + 1];
    if (r0 == r1) return;
    float tcol[32];
    const __half* Tp = T + (size_t)src * 1024 + o;
    #pragma unroll
    for (int j = 0; j < 32; ++j) tcol[j] = __half2float(Tp[j * 32]);
    float xbv = xb[src * 32 + o];
    for (int r = r0; r < r1; ++r) {
        int dst = cdst[r];
        const __half2* hp2 = (const __half2*)(hEs + (size_t)r * 32);
        float m = xbv;
        #pragma unroll
        for (int jj = 0; jj < 16; ++jj) {
            float2 hv = __half22float2(hp2[jj]);
            m += hv.x * tcol[2 * jj] + hv.y * tcol[2 * jj + 1];
        }
        atomicAdd(&agg[dst * 32 + o], m);
    }
}

// h0 = relu(agg/deg + x@root_w + bias) -> fp16, fused layer1 es/ed/mkey
__global__ __launch_bounds__(256) void k_h0e(const float* __restrict__ x,
                                             const float* __restrict__ root_w,
                                             const float* __restrict__ nn_bias,
                                             const float* __restrict__ agg,
                                             const int* __restrict__ rowptr,
                                             const float* __restrict__ wa,
                                             const float* __restrict__ wd,
                                             __half* __restrict__ h0f,
                                             float* __restrict__ es,
                                             float* __restrict__ ed,
                                             int* __restrict__ mkey) {
    int t = threadIdx.x;
    int ng = t >> 5, o = t & 31;
    int n = blockIdx.x * 8 + ng;
    if (n >= N_NODES) return;
    float s = nn_bias[o];
    for (int k = 0; k < IN_DIM; ++k) s += x[n * IN_DIM + k] * root_w[k * 32 + o];
    float c = fmaxf((float)(rowptr[n + 1] - rowptr[n]), 1.f);
    s += agg[n * IN_DIM + o] / c;
    float v = fmaxf(s, 0.f);
    h0f[n * IN_DIM + o] = __float2half(v);
    #pragma unroll
    for (int h = 0; h < 4; ++h) {
        float ss = v * wa[h * 32 + o];
        float dd = v * wd[h * 32 + o];
        #pragma unroll
        for (int off = 16; off; off >>= 1) {
            ss += __shfl_down(ss, off, 32);
            dd += __shfl_down(dd, off, 32);
        }
        if (o == 0) {
            es[n * 4 + h] = ss; ed[n * 4 + h] = dd;
            mkey[n * 4 + h] = fkey(leaky(ss + dd));
        }
    }
}

// ---------------------------------------------------------------- GEMM 1: T = xf @ wtt^T, out [M,1024] fp16
__global__ __launch_bounds__(256, 2) void k_gemT(const __half* __restrict__ A,
                                                 const __half* __restrict__ Wt,
                                                 __half* __restrict__ C) {
    __shared__ __half cst[4][16 * 36];
    int t = threadIdx.x, wid = t >> 6, lane = t & 63;
    int lr = lane & 15, lk = (lane >> 4) * 8;

    int bid = blockIdx.x;
    int xcd = bid & 7, j = bid >> 3;
    int sx = j & 31;
    int y = ((j >> 5) << 3) | xcd;            // 0..103
    int n0 = sx * 32;

    half8v bfr[2];
    #pragma unroll
    for (int c = 0; c < 2; ++c) {
        float4 raw = *(const float4*)(Wt + (size_t)(n0 + c * 16 + lr) * 32 + lk);
        pin4(raw);
        bfr[c] = __builtin_bit_cast(half8v, raw);
    }

    int tb = (y * 4 + wid) * 4;
    for (int pp = 0; pp < 4; pp += 2) {
        int tA = tb + pp;
        if (tA >= N_TILES) break;
        int mA = tA * 16, mB = mA + 16;
        half8v aA = *(const half8v*)(A + (size_t)(mA + lr) * 32 + lk);
        half8v aB = *(const half8v*)(A + (size_t)(mB + lr) * 32 + lk);
        f32x4 acc[2][2];
        #pragma unroll
        for (int i = 0; i < 2; ++i)
            #pragma unroll
            for (int c = 0; c < 2; ++c)
                acc[i][c] = (f32x4){0.f, 0.f, 0.f, 0.f};
        acc[0][0] = __builtin_amdgcn_mfma_f32_16x16x32_f16(aA, bfr[0], acc[0][0], 0, 0, 0);
        acc[0][1] = __builtin_amdgcn_mfma_f32_16x16x32_f16(aA, bfr[1], acc[0][1], 0, 0, 0);
        acc[1][0] = __builtin_amdgcn_mfma_f32_16x16x32_f16(aB, bfr[0], acc[1][0], 0, 0, 0);
        acc[1][1] = __builtin_amdgcn_mfma_f32_16x16x32_f16(aB, bfr[1], acc[1][1], 0, 0, 0);

        int rbase = (lane >> 4) * 4;
        #pragma unroll
        for (int ti = 0; ti < 2; ++ti) {
            #pragma unroll
            for (int c = 0; c < 2; ++c)
                #pragma unroll
                for (int r = 0; r < 4; ++r)
                    cst[wid][(rbase + r) * 36 + c * 16 + lr] = __float2half(acc[ti][c][r]);
            int m0 = ti ? mB : mA;
            #pragma unroll
            for (int p = 0; p < 2; ++p) {
                int row = p * 8 + (lane >> 3), hb = lane & 7;
                float2 v = *(const float2*)((const char*)&cst[wid][0] + row * 72 + hb * 8);
                *(float2*)((char*)C + ((size_t)(m0 + row) * 1024 + n0) * 2 + hb * 8) = v;
            }
        }
    }
}

// ---------------------------------------------------------------- GEMM 2: head-mean-folded, out [M,256]
// C = relu(A[M,K] @ Wt[256,K]^T + bias). One tile-pair per wave for max TLP.
// bid = xcd + 8*(strip + 8*yq); y = yq*8+xcd -> same pair-group y on one XCD.
template <int K, typename OT>
__global__ __launch_bounds__(256, 1) void k_gemmo(const __half* __restrict__ A,
                                                  const __half* __restrict__ Wt,
                                                  const float* __restrict__ bias,
                                                  OT* __restrict__ C) {
    constexpr int CK  = 128;                    // k-chunk
    constexpr int KC  = K / CK;
    constexpr int KSC = CK / 32;
    __shared__ float cst[4][16 * 36];
    int t = threadIdx.x, wid = t >> 6, lane = t & 63;
    int lr = lane & 15, lk = (lane >> 4) * 8;

    int bid = blockIdx.x;
    int xcd = bid & 7, rest = bid >> 3;
    int strip = rest & 7, yq = rest >> 3;
    int y = yq * 8 + xcd;                       // pair-group 0..195
    if (y >= 196) return;
    int p = y * 4 + wid;                        // pair index
    if (p >= N_PAIRS) return;
    int n0 = strip * 32;
    float bv0 = bias[n0 + lr], bv1 = bias[n0 + 16 + lr];

    int mA = p * 32, mB = mA + 16;
    f32x4 acc[2][2];
    #pragma unroll
    for (int i = 0; i < 2; ++i)
        #pragma unroll
        for (int c = 0; c < 2; ++c)
            acc[i][c] = (f32x4){0.f, 0.f, 0.f, 0.f};

    #pragma unroll
    for (int kc = 0; kc < KC; ++kc) {
        half8v bfr[KSC][2];
        #pragma unroll
        for (int ks = 0; ks < KSC; ++ks)
            #pragma unroll
            for (int c = 0; c < 2; ++c) {
                float4 raw = *(const float4*)(Wt + (size_t)(n0 + c * 16 + lr) * K + kc * CK + ks * 32 + lk);
                pin4(raw);
                bfr[ks][c] = __builtin_bit_cast(half8v, raw);
            }
        const __half* pA = A + (size_t)(mA + lr) * K + kc * CK + lk;
        const __half* pB = A + (size_t)(mB + lr) * K + kc * CK + lk;
        #pragma unroll
        for (int ks = 0; ks < KSC; ++ks) {
            half8v aA = *(const half8v*)(pA + (size_t)ks * 32);
            half8v aB = *(const half8v*)(pB + (size_t)ks * 32);
            acc[0][0] = __builtin_amdgcn_mfma_f32_16x16x32_f16(aA, bfr[ks][0], acc[0][0], 0, 0, 0);
            acc[0][1] = __builtin_amdgcn_mfma_f32_16x16x32_f16(aA, bfr[ks][1], acc[0][1], 0, 0, 0);
            acc[1][0] = __builtin_amdgcn_mfma_f32_16x16x32_f16(aB, bfr[ks][0], acc[1][0], 0, 0, 0);
            acc[1][1] = __builtin_amdgcn_mfma_f32_16x16x32_f16(aB, bfr[ks][1], acc[1][1], 0, 0, 0);
        }
    }

    int rbase = (lane >> 4) * 4;
    #pragma unroll
    for (int ti = 0; ti < 2; ++ti) {
        #pragma unroll
        for (int c = 0; c < 2; ++c)
            #pragma unroll
            for (int r = 0; r < 4; ++r)
                cst[wid][(rbase + r) * 36 + c * 16 + lr] =
                    fmaxf(acc[ti][c][r] + (c ? bv1 : bv0), 0.f);
        int m0 = ti ? mB : mA;
        int row = lane >> 2, cg = lane & 3;   // 16 rows x 4 col-groups of 8
        const float* sp = &cst[wid][row * 36 + cg * 8];
        if constexpr (sizeof(OT) == 2) {
            __half2 o0 = __float22half2_rn(make_float2(sp[0], sp[1]));
            __half2 o1 = __float22half2_rn(make_float2(sp[2], sp[3]));
            __half2 o2 = __float22half2_rn(make_float2(sp[4], sp[5]));
            __half2 o3 = __float22half2_rn(make_float2(sp[6], sp[7]));
            float4 v = make_float4(__uint_as_float(*(unsigned*)&o0), __uint_as_float(*(unsigned*)&o1),
                                   __uint_as_float(*(unsigned*)&o2), __uint_as_float(*(unsigned*)&o3));
            *(float4*)((__half*)C + (size_t)(m0 + row) * 256 + n0 + cg * 8) = v;
        } else {
            float4 v0 = make_float4(sp[0], sp[1], sp[2], sp[3]);
            float4 v1 = make_float4(sp[4], sp[5], sp[6], sp[7]);
            float* cp = (float*)C + (size_t)(m0 + row) * 256 + n0 + cg * 8;
            *(float4*)cp = v0;
            *(float4*)(cp + 4) = v1;
        }
    }
}

// ---------------------------------------------------------------- attention scalars
__global__ __launch_bounds__(256) void k_esed2(const __half* __restrict__ h1f,
                                               const float* __restrict__ wa,
                                               const float* __restrict__ wd,
                                               float* __restrict__ es,
                                               float* __restrict__ ed,
                                               int* __restrict__ mkey) {
    int n = blockIdx.x;
    int h = threadIdx.x >> 6, lane = threadIdx.x & 63;
    float s = 0.f, d2 = 0.f;
    for (int d = lane; d < 256; d += 64) {
        float v = __half2float(h1f[(size_t)n * 256 + d]);
        s  += v * wa[h * 256 + d];
        d2 += v * wd[h * 256 + d];
    }
    #pragma unroll
    for (int off = 32; off; off >>= 1) {
        s  += __shfl_down(s, off);
        d2 += __shfl_down(d2, off);
    }
    if (lane == 0) {
        es[n * 4 + h] = s; ed[n * 4 + h] = d2;
        mkey[n * 4 + h] = fkey(leaky(s + d2));
    }
}

__global__ __launch_bounds__(256) void k_mmax(const int* __restrict__ ei,
                                              const float* __restrict__ es,
                                              const float* __restrict__ ed,
                                              int* __restrict__ mkey) {
    int idx = blockIdx.x * 256 + threadIdx.x;
    if (idx >= N_EDGES * 4) return;
    int e = idx >> 2, h = idx & 3;
    int src = ei[e], dst = ei[N_EDGES + e];
    atomicMax(&mkey[dst * 4 + h], fkey(leaky(es[src * 4 + h] + ed[dst * 4 + h])));
}

__global__ __launch_bounds__(256) void k_watt(const int* __restrict__ ei,
                                              const int* __restrict__ epos,
                                              const float* __restrict__ es,
                                              const float* __restrict__ ed,
                                              const int* __restrict__ mkey,
                                              float* __restrict__ wv,
                                              float* __restrict__ den) {
    int idx = blockIdx.x * 256 + threadIdx.x;
    if (idx >= N_EDGES * 4) return;
    int e = idx >> 2, h = idx & 3;
    int src = ei[e], dst = ei[N_EDGES + e];
    float v = leaky(es[src * 4 + h] + ed[dst * 4 + h]);
    float w = __expf(v - funkey(mkey[dst * 4 + h]));
    wv[(size_t)epos[e] * 4 + h] = w;
    atomicAdd(&den[dst * 4 + h], w);
}

// ---------------------------------------------------------------- pre-GEMM aggregation
__global__ __launch_bounds__(256) void k_agg1(const int* __restrict__ rowptr,
                                              const int* __restrict__ csrc,
                                              const float* __restrict__ es,
                                              const float* __restrict__ ed,
                                              const int* __restrict__ mkey,
                                              const float* __restrict__ denb,
                                              const float* __restrict__ wv,
                                              const __half* __restrict__ h0f,
                                              __half* __restrict__ agg0) {
    int dst = blockIdx.x * 4 + (threadIdx.x >> 6);
    if (dst >= N_NODES) return;
    int lane = threadIdx.x & 63;
    int h = lane >> 4, i2 = lane & 15;
    float m = funkey(mkey[dst * 4 + h]);
    float vself = leaky(es[dst * 4 + h] + ed[dst * 4 + h]);
    float ws = __expf(vself - m);
    float dn = denb[dst * 4 + h] + ws;
    int r0 = rowptr[dst], r1 = rowptr[dst + 1];

    __half2 hv = *(const __half2*)(h0f + (size_t)dst * 32 + i2 * 2);
    float2 f = __half22float2(hv);
    float ax = ws * f.x, ay = ws * f.y;
    for (int r = r0; r < r1; ++r) {
        int src = csrc[r];
        float w = wv[(size_t)r * 4 + h];
        __half2 sv = *(const __half2*)(h0f + (size_t)src * 32 + i2 * 2);
        float2 g = __half22float2(sv);
        ax += w * g.x; ay += w * g.y;
    }
    float inv = 1.f / (dn + 1e-16f);
    *(__half2*)(agg0 + (size_t)dst * 128 + h * 32 + i2 * 2) =
        __float22half2_rn(make_float2(ax * inv, ay * inv));
}

__global__ __launch_bounds__(256) void k_agg2(const int* __restrict__ rowptr,
                                              const int* __restrict__ csrc,
                                              const float* __restrict__ es,
                                              const float* __restrict__ ed,
                                              const int* __restrict__ mkey,
                                              const float* __restrict__ denb,
                                              const float* __restrict__ wv,
                                              const __half* __restrict__ h1f,
                                              __half* __restrict__ agg1) {
    int dst = blockIdx.x * 4 + (threadIdx.x >> 6);
    if (dst >= N_NODES) return;
    int lane = threadIdx.x & 63;
    float ws[4], dn[4];
    #pragma unroll
    for (int h = 0; h < 4; ++h) {
        float m = funkey(mkey[dst * 4 + h]);
        float vself = leaky(es[dst * 4 + h] + ed[dst * 4 + h]);
        ws[h] = __expf(vself - m);
        dn[h] = denb[dst * 4 + h] + ws[h];
    }
    int r0 = rowptr[dst], r1 = rowptr[dst + 1];

    float acc[4][4];
    {
        float2 q = *(const float2*)(h1f + (size_t)dst * 256 + lane * 4);
        const __half2* hq = (const __half2*)&q;
        float2 f0 = __half22float2(hq[0]), f1 = __half22float2(hq[1]);
        #pragma unroll
        for (int h = 0; h < 4; ++h) {
            acc[h][0] = ws[h] * f0.x; acc[h][1] = ws[h] * f0.y;
            acc[h][2] = ws[h] * f1.x; acc[h][3] = ws[h] * f1.y;
        }
    }
    for (int r = r0; r < r1; ++r) {
        int src = csrc[r];
        float4 w4 = *(const float4*)(wv + (size_t)r * 4);
        float2 q = *(const float2*)(h1f + (size_t)src * 256 + lane * 4);
        const __half2* hq = (const __half2*)&q;
        float2 f0 = __half22float2(hq[0]), f1 = __half22float2(hq[1]);
        acc[0][0] += w4.x * f0.x; acc[0][1] += w4.x * f0.y; acc[0][2] += w4.x * f1.x; acc[0][3] += w4.x * f1.y;
        acc[1][0] += w4.y * f0.x; acc[1][1] += w4.y * f0.y; acc[1][2] += w4.y * f1.x; acc[1][3] += w4.y * f1.y;
        acc[2][0] += w4.z * f0.x; acc[2][1] += w4.z * f0.y; acc[2][2] += w4.z * f1.x; acc[2][3] += w4.z * f1.y;
        acc[3][0] += w4.w * f0.x; acc[3][1] += w4.w * f0.y; acc[3][2] += w4.w * f1.x; acc[3][3] += w4.w * f1.y;
    }
    #pragma unroll
    for (int h = 0; h < 4; ++h) {
        float inv = 1.f / (dn[h] + 1e-16f);
        __half2 o0 = __float22half2_rn(make_float2(acc[h][0] * inv, acc[h][1] * inv));
        __half2 o1 = __float22half2_rn(make_float2(acc[h][2] * inv, acc[h][3] * inv));
        __half2* op = (__half2*)(agg1 + (size_t)dst * 1024 + h * 256 + lane * 4);
        op[0] = o0; op[1] = o1;
    }
}

// ---------------------------------------------------------------- heads
__global__ __launch_bounds__(256) void k_wire(const int* __restrict__ wm,
                                              const float* __restrict__ h2,
                                              const float* __restrict__ ww,
                                              const float* __restrict__ wb,
                                              float* __restrict__ out) {
    int k = blockIdx.x * 4 + (threadIdx.x >> 6);
    int lane = threadIdx.x & 63;
    if (k >= KWIRE) return;
    int n = wm[k];
    float s = 0.f;
    for (int d = lane; d < 256; d += 64) s += h2[(size_t)n * 256 + d] * ww[d];
    #pragma unroll
    for (int off = 32; off; off >>= 1) s += __shfl_down(s, off);
    if (lane == 0) out[k] = s + wb[0];
}

__global__ __launch_bounds__(256) void k_pool(const float* __restrict__ h2,
                                              const int* __restrict__ batch,
                                              float* __restrict__ pooled,
                                              float* __restrict__ gcnt) {
    int n0 = blockIdx.x * POOL_NB;
    int n1 = n0 + POOL_NB; if (n1 > N_NODES) n1 = N_NODES;
    int d = threadIdx.x;
    int cur = batch[n0];
    float acc = 0.f, cnt = 0.f;
    for (int n = n0; n < n1; ++n) {
        int g = batch[n];
        if (g != cur) {
            atomicAdd(&pooled[cur * 256 + d], acc);
            if (d == 0) atomicAdd(&gcnt[cur], cnt);
            acc = 0.f; cnt = 0.f; cur = g;
        }
        acc += h2[(size_t)n * 256 + d];
        cnt += 1.f;
    }
    atomicAdd(&pooled[cur * 256 + d], acc);
    if (d == 0) atomicAdd(&gcnt[cur], cnt);
}

__global__ __launch_bounds__(256) void k_act(const float* __restrict__ pooled,
                                             const float* __restrict__ gcnt,
                                             const float* __restrict__ aw,
                                             const float* __restrict__ ab,
                                             float* __restrict__ out) {
    int u = blockIdx.x * 4 + (threadIdx.x >> 6);
    int lane = threadIdx.x & 63;
    if (u >= NGRAPH * NACT) return;
    int g = u >> 4, a = u & 15;
    float c = fmaxf(gcnt[g], 1.f);
    float s = 0.f;
    for (int d = lane; d < 256; d += 64) s += pooled[g * 256 + d] * aw[d * 16 + a];
    #pragma unroll
    for (int off = 32; off; off >>= 1) s += __shfl_down(s, off);
    if (lane == 0) out[KWIRE + u] = s / c + ab[a];
}

// ---------------------------------------------------------------- launch
extern "C" void kernel_launch(void* const* d_in, const int* in_sizes, int n_in,
                              void* d_out, int out_size, void* d_ws, size_t ws_size,
                              hipStream_t stream) {
    const float* x        = (const float*)d_in[0];
    const float* edge_attr= (const float*)d_in[1];
    const int*   wire_mask= (const int*)d_in[2];
    const int*   edge_idx = (const int*)d_in[3];
    const int*   batch    = (const int*)d_in[4];
    const float* enc_w1   = (const float*)d_in[5];
    const float* enc_b1   = (const float*)d_in[6];
    const float* enc_w2   = (const float*)d_in[7];
    const float* enc_b2   = (const float*)d_in[8];
    const float* root_w   = (const float*)d_in[9];
    const float* nn_bias  = (const float*)d_in[10];
    const float* gat1_w   = (const float*)d_in[11];
    const float* gat1_asrc= (const float*)d_in[12];
    const float* gat1_adst= (const float*)d_in[13];
    const float* gat1_b   = (const float*)d_in[14];
    const float* gat2_w   = (const float*)d_in[15];
    const float* gat2_asrc= (const float*)d_in[16];
    const float* gat2_adst= (const float*)d_in[17];
    const float* gat2_b   = (const float*)d_in[18];
    const float* wire_w   = (const float*)d_in[19];
    const float* wire_b   = (const float*)d_in[20];
    const float* act_w    = (const float*)d_in[21];
    const float* act_b    = (const float*)d_in[22];
    float* out = (float*)d_out;

    float* ws = (float*)d_ws;
    size_t off = 0;
    __half* T16   = (__half*)(ws + off); off += (size_t)M_PAD * 1024 / 2;
    __half* agg1f = (__half*)(ws + off); off += (size_t)M_PAD * 1024 / 2;
    __half* agg0f = (__half*)(ws + off); off += (size_t)M_PAD * 128 / 2;
    __half* h0f   = (__half*)(ws + off); off += (size_t)M_PAD * 32 / 2;
    __half* h1f   = (__half*)(ws + off); off += (size_t)M_PAD * 256 / 2;
    __half* xf    = (__half*)(ws + off); off += (size_t)M_PAD * 32 / 2;
    __half* hEs   = (__half*)(ws + off); off += (size_t)N_EDGES * 32 / 2;
    float* xb     = ws + off; off += 800000;
    float* agg    = ws + off; off += 800000;
    float* esb    = ws + off; off += 100000;
    float* edb    = ws + off; off += 100000;
    float* h2     = ws + off; off += (size_t)M_PAD * 256;
    float* pooled = ws + off; off += NGRAPH * 256;
    float* gcnt   = ws + off; off += NGRAPH;
    int* deg      = (int*)(ws + off); off += 25600;   // zero-region start
    int* deg2     = (int*)(ws + off); off += 25600;
    int* cursor   = (int*)(ws + off); off += 25600;
    int* cursor2  = (int*)(ws + off); off += 25600;   // zero-region end
    int* rowptr   = (int*)(ws + off); off += 25600;
    int* rowptr2  = (int*)(ws + off); off += 25600;
    int* csrc     = (int*)(ws + off); off += N_EDGES;
    int* epos     = (int*)(ws + off); off += N_EDGES;
    int* cdst     = (int*)(ws + off); off += N_EDGES;
    int* epos2    = (int*)(ws + off); off += N_EDGES;
    int* mkey     = (int*)(ws + off); off += 100000;
    float* den    = ws + off; off += 100000;
    float* wv     = ws + off; off += (size_t)N_EDGES * 4;
    __half* wtt   = (__half*)(ws + off); off += 16384;    // enc_w2 perm [1024][32]
    __half* wb1t  = (__half*)(ws + off); off += 16384;    // [256][128]
    __half* wb2t  = (__half*)(ws + off); off += 131072;   // [256][1024]
    float* wa1    = ws + off; off += 128;
    float* wd1    = ws + off; off += 128;
    float* wa2    = ws + off; off += 1024;
    float* wd2    = ws + off; off += 1024;

    const int EH = N_EDGES * 4;
    const int GBT = 3328;   // T-gemm: 8 xcd x 13 ygroups x 32 strips
    const int GBO = 1600;   // out-256 gemms: 8 xcd x 8 strips x 25 yq (y>=196 idle)

    // ---- CSR build ----
    hipMemsetAsync(deg, 0, 4 * 25600 * sizeof(int), stream);
    k_deg2<<<(N_EDGES + 255) / 256, 256, 0, stream>>>(edge_idx, deg, deg2);
    k_scan2<<<2, 256, 0, stream>>>(deg, rowptr, deg2, rowptr2);
    k_scatter2<<<(N_EDGES + 255) / 256, 256, 0, stream>>>(edge_idx, rowptr, rowptr2,
                                                          cursor, cursor2, csrc, epos, cdst, epos2);

    // ---- weight prep ----
    k_w2perm<<<(32 * 1024 + 255) / 256, 256, 0, stream>>>(enc_w2, wtt);
    k_wb1<<<(256 * 128 + 255) / 256, 256, 0, stream>>>(gat1_w, wb1t);
    k_wb2<<<(256 * 1024 + 255) / 256, 256, 0, stream>>>(gat2_w, wb2t);
    k_xcvt<<<(N_NODES * 32 + 255) / 256, 256, 0, stream>>>(x, enc_b2, xf, xb);
    k_wa1<<<1, 128, 0, stream>>>(gat1_w, gat1_asrc, gat1_adst, wa1, wd1);
    k_wa2<<<4, 256, 0, stream>>>(gat2_w, gat2_asrc, gat2_adst, wa2, wd2);

    // ---- NNConv ----
    hipMemsetAsync(agg, 0, 800000 * sizeof(float), stream);
    k_gemT<<<GBT, 256, 0, stream>>>(xf, wtt, T16);
    k_hedge<<<(N_EDGES + 7) / 8, 256, 0, stream>>>(edge_attr, enc_w1, enc_b1, epos2, hEs);
    k_msg2<<<(N_NODES + 7) / 8, 256, 0, stream>>>(rowptr2, cdst, hEs, T16, xb, agg);
    k_h0e<<<(N_NODES + 7) / 8, 256, 0, stream>>>(x, root_w, nn_bias, agg, rowptr,
                                                 wa1, wd1, h0f, esb, edb, mkey);

    // ---- GAT layer 1 ----
    k_mmax<<<(EH + 255) / 256, 256, 0, stream>>>(edge_idx, esb, edb, mkey);
    hipMemsetAsync(den, 0, 100000 * sizeof(float), stream);
    k_watt<<<(EH + 255) / 256, 256, 0, stream>>>(edge_idx, epos, esb, edb, mkey, wv, den);
    k_agg1<<<(N_NODES + 3) / 4, 256, 0, stream>>>(rowptr, csrc, esb, edb, mkey, den, wv, h0f, agg0f);
    k_gemmo<128, __half><<<GBO, 256, 0, stream>>>(agg0f, wb1t, gat1_b, h1f);
    k_esed2<<<N_NODES, 256, 0, stream>>>(h1f, wa2, wd2, esb, edb, mkey);

    // ---- GAT layer 2 ----
    k_mmax<<<(EH + 255) / 256, 256, 0, stream>>>(edge_idx, esb, edb, mkey);
    hipMemsetAsync(den, 0, 100000 * sizeof(float), stream);
    k_watt<<<(EH + 255) / 256, 256, 0, stream>>>(edge_idx, epos, esb, edb, mkey, wv, den);
    k_agg2<<<(N_NODES + 3) / 4, 256, 0, stream>>>(rowptr, csrc, esb, edb, mkey, den, wv, h1f, agg1f);
    k_gemmo<1024, float><<<GBO, 256, 0, stream>>>(agg1f, wb2t, gat2_b, h2);

    // ---- heads ----
    k_wire<<<KWIRE / 4, 256, 0, stream>>>(wire_mask, h2, wire_w, wire_b, out);
    hipMemsetAsync(pooled, 0, (NGRAPH * 256 + NGRAPH) * sizeof(float), stream);
    k_pool<<<(N_NODES + POOL_NB - 1) / POOL_NB, 256, 0, stream>>>(h2, batch, pooled, gcnt);
    k_act<<<NGRAPH * NACT / 4, 256, 0, stream>>>(pooled, gcnt, act_w, act_b, out);
}

// Round 17
// 541.464 us; speedup vs baseline: 1.1139x; 1.0774x over previous
//
#include <hip/hip_runtime.h>
#include <hip/hip_fp16.h>

#define N_NODES 25000
#define M_PAD   25024            // multiple of 16 (1564 tiles)
#define N_TILES 1564
#define N_EDGES 300000
#define IN_DIM  32
#define EDFD    16
#define HIDD    256
#define HEADS   4
#define NACT    16
#define NGRAPH  64
#define KWIRE   1024
#define POOL_NB 64

typedef _Float16 half8v __attribute__((ext_vector_type(8)));
typedef __attribute__((ext_vector_type(4))) float f32x4;

// ---------------------------------------------------------------- helpers
__device__ __forceinline__ float leaky(float v) { return v > 0.f ? v : 0.2f * v; }
__device__ __forceinline__ int fkey(float f) {
    int b = __float_as_int(f);
    b ^= (b >> 31) & 0x7fffffff;
    return b;
}
__device__ __forceinline__ float funkey(int b) {
    b ^= (b >> 31) & 0x7fffffff;
    return __int_as_float(b);
}

// ---------------------------------------------------------------- CSR build (both directions)
__global__ __launch_bounds__(256) void k_deg2(const int* __restrict__ ei,
                                              int* __restrict__ deg,
                                              int* __restrict__ deg2) {
    int e = blockIdx.x * 256 + threadIdx.x;
    if (e >= N_EDGES) return;
    atomicAdd(&deg[ei[N_EDGES + e]], 1);
    atomicAdd(&deg2[ei[e]], 1);
}

__global__ __launch_bounds__(256) void k_scan2(const int* __restrict__ degA, int* __restrict__ rpA,
                                               const int* __restrict__ degB, int* __restrict__ rpB) {
    const int* deg = blockIdx.x ? degB : degA;
    int* rowptr    = blockIdx.x ? rpB : rpA;
    __shared__ int part[256];
    int t = threadIdx.x;
    const int CH = 98;
    int base = t * CH;
    int s = 0;
    for (int i = 0; i < CH; ++i) {
        int idx = base + i;
        if (idx < N_NODES) s += deg[idx];
    }
    part[t] = s;
    __syncthreads();
    if (t == 0) {
        int run = 0;
        for (int i = 0; i < 256; ++i) { int v = part[i]; part[i] = run; run += v; }
    }
    __syncthreads();
    int run = part[t];
    for (int i = 0; i < CH; ++i) {
        int idx = base + i;
        if (idx < N_NODES) { rowptr[idx] = run; run += deg[idx]; }
    }
    if (N_NODES >= base && N_NODES < base + CH) rowptr[N_NODES] = run;
}

__global__ __launch_bounds__(256) void k_scatter2(const int* __restrict__ ei,
                                                  const int* __restrict__ rowptr,
                                                  const int* __restrict__ rowptr2,
                                                  int* __restrict__ cursor,
                                                  int* __restrict__ cursor2,
                                                  int* __restrict__ csrc,
                                                  int* __restrict__ epos,
                                                  int* __restrict__ cdst,
                                                  int* __restrict__ epos2) {
    int e = blockIdx.x * 256 + threadIdx.x;
    if (e >= N_EDGES) return;
    int src = ei[e], dst = ei[N_EDGES + e];
    int p1 = atomicAdd(&cursor[dst], 1);
    int r1 = rowptr[dst] + p1;
    csrc[r1] = src;
    epos[e] = r1;
    int p2 = atomicAdd(&cursor2[src], 1);
    int r2 = rowptr2[src] + p2;
    cdst[r2] = dst;
    epos2[e] = r2;
}

// ---------------------------------------------------------------- weight prep
__global__ __launch_bounds__(256) void k_w2perm(const float* __restrict__ w2,
                                                __half* __restrict__ Wt) {
    int idx = blockIdx.x * 256 + threadIdx.x;   // co*32 + i
    if (idx >= 32 * 1024) return;
    int co = idx >> 5, i = idx & 31;
    Wt[idx] = __float2half(w2[(co >> 5) * 1024 + i * 32 + (co & 31)]);
}

// head-mean-folded weights: Wb1[d][k], k=h*32+i ; value 0.25*W1[i, h*256+d]
__global__ __launch_bounds__(256) void k_wb1(const float* __restrict__ W1,
                                             __half* __restrict__ Wb) {
    int idx = blockIdx.x * 256 + threadIdx.x;   // d*128+k
    if (idx >= 256 * 128) return;
    int d = idx >> 7, k = idx & 127;
    int h = k >> 5, i = k & 31;
    Wb[idx] = __float2half(0.25f * W1[i * 1024 + h * 256 + d]);
}

// Wb2[d][k], k=h*256+i ; value 0.25*W2[i, h*256+d]
__global__ __launch_bounds__(256) void k_wb2(const float* __restrict__ W2,
                                             __half* __restrict__ Wb) {
    int idx = blockIdx.x * 256 + threadIdx.x;   // d*1024+k
    if (idx >= 256 * 1024) return;
    int d = idx >> 10, k = idx & 1023;
    int h = k >> 8, i = k & 255;
    Wb[idx] = __float2half(0.25f * W2[i * 1024 + h * 256 + d]);
}

__global__ __launch_bounds__(128) void k_wa1(const float* __restrict__ W1,
                                             const float* __restrict__ asrc,
                                             const float* __restrict__ adst,
                                             float* __restrict__ wa,
                                             float* __restrict__ wd) {
    int t = threadIdx.x;            // h*32+i
    int h = t >> 5, i = t & 31;
    float s = 0.f, sd = 0.f;
    for (int d = 0; d < 256; ++d) {
        float w = W1[i * 1024 + h * 256 + d];
        s  += w * asrc[h * 256 + d];
        sd += w * adst[h * 256 + d];
    }
    wa[t] = s; wd[t] = sd;
}

__global__ __launch_bounds__(256) void k_wa2(const float* __restrict__ W2,
                                             const float* __restrict__ asrc,
                                             const float* __restrict__ adst,
                                             float* __restrict__ wa,
                                             float* __restrict__ wd) {
    int idx = blockIdx.x * 256 + threadIdx.x;   // h*256+i
    if (idx >= 1024) return;
    int h = idx >> 8, i = idx & 255;
    float s = 0.f, sd = 0.f;
    for (int d = 0; d < 256; ++d) {
        float w = W2[i * 1024 + h * 256 + d];
        s  += w * asrc[h * 256 + d];
        sd += w * adst[h * 256 + d];
    }
    wa[idx] = s; wd[idx] = sd;
}

__global__ __launch_bounds__(256) void k_xcvt(const float* __restrict__ x,
                                              const float* __restrict__ b2,
                                              __half* __restrict__ xf,
                                              float* __restrict__ xb) {
    int idx = blockIdx.x * 256 + threadIdx.x;
    if (idx >= N_NODES * 32) return;
    int n = idx >> 5, o = idx & 31;
    xf[idx] = __float2half(x[idx]);
    float s = 0.f;
    for (int i = 0; i < 32; ++i) s += x[n * 32 + i] * b2[i * 32 + o];
    xb[idx] = s;
}

// ---------------------------------------------------------------- NNConv
__global__ __launch_bounds__(256) void k_hedge(const float* __restrict__ ea,
                                               const float* __restrict__ w1,
                                               const float* __restrict__ b1,
                                               const int* __restrict__ epos2,
                                               __half* __restrict__ hEs) {
    int t = threadIdx.x;
    int eg = t >> 5, o = t & 31;
    int e = blockIdx.x * 8 + eg;
    if (e >= N_EDGES) return;
    float a = b1[o];
    for (int k = 0; k < EDFD; ++k) a += ea[e * EDFD + k] * w1[k * 32 + o];
    hEs[(size_t)epos2[e] * 32 + o] = __float2half(fmaxf(a, 0.f));
}

__global__ __launch_bounds__(256) void k_msg2(const int* __restrict__ rowptr2,
                                              const int* __restrict__ cdst,
                                              const __half* __restrict__ hEs,
                                              const __half* __restrict__ T,
                                              const float* __restrict__ xb,
                                              float* __restrict__ agg) {
    int g = threadIdx.x >> 5, o = threadIdx.x & 31;
    int src = blockIdx.x * 8 + g;
    if (src >= N_NODES) return;
    int r0 = rowptr2[src], r1 = rowptr2[src + 1];
    if (r0 == r1) return;
    float tcol[32];
    const __half* Tp = T + (size_t)src * 1024 + o;
    #pragma unroll
    for (int j = 0; j < 32; ++j) tcol[j] = __half2float(Tp[j * 32]);
    float xbv = xb[src * 32 + o];
    for (int r = r0; r < r1; ++r) {
        int dst = cdst[r];
        const __half2* hp2 = (const __half2*)(hEs + (size_t)r * 32);
        float m = xbv;
        #pragma unroll
        for (int jj = 0; jj < 16; ++jj) {
            float2 hv = __half22float2(hp2[jj]);
            m += hv.x * tcol[2 * jj] + hv.y * tcol[2 * jj + 1];
        }
        atomicAdd(&agg[dst * 32 + o], m);
    }
}

// h0 = relu(agg/deg + x@root_w + bias) -> fp16, fused layer1 es/ed/mkey
__global__ __launch_bounds__(256) void k_h0e(const float* __restrict__ x,
                                             const float* __restrict__ root_w,
                                             const float* __restrict__ nn_bias,
                                             const float* __restrict__ agg,
                                             const int* __restrict__ rowptr,
                                             const float* __restrict__ wa,
                                             const float* __restrict__ wd,
                                             __half* __restrict__ h0f,
                                             float* __restrict__ es,
                                             float* __restrict__ ed,
                                             int* __restrict__ mkey) {
    int t = threadIdx.x;
    int ng = t >> 5, o = t & 31;
    int n = blockIdx.x * 8 + ng;
    if (n >= N_NODES) return;
    float s = nn_bias[o];
    for (int k = 0; k < IN_DIM; ++k) s += x[n * IN_DIM + k] * root_w[k * 32 + o];
    float c = fmaxf((float)(rowptr[n + 1] - rowptr[n]), 1.f);
    s += agg[n * IN_DIM + o] / c;
    float v = fmaxf(s, 0.f);
    h0f[n * IN_DIM + o] = __float2half(v);
    #pragma unroll
    for (int h = 0; h < 4; ++h) {
        float ss = v * wa[h * 32 + o];
        float dd = v * wd[h * 32 + o];
        #pragma unroll
        for (int off = 16; off; off >>= 1) {
            ss += __shfl_down(ss, off, 32);
            dd += __shfl_down(dd, off, 32);
        }
        if (o == 0) {
            es[n * 4 + h] = ss; ed[n * 4 + h] = dd;
            mkey[n * 4 + h] = fkey(leaky(ss + dd));
        }
    }
}

// ---------------------------------------------------------------- GEMM 1: T = xf @ wtt^T, out [M,1024] fp16
__global__ __launch_bounds__(256, 2) void k_gemT(const __half* __restrict__ A,
                                                 const __half* __restrict__ Wt,
                                                 __half* __restrict__ C) {
    __shared__ __half cst[4][16 * 36];
    int t = threadIdx.x, wid = t >> 6, lane = t & 63;
    int lr = lane & 15, lk = (lane >> 4) * 8;

    int bid = blockIdx.x;
    int xcd = bid & 7, j = bid >> 3;
    int sx = j & 31;
    int y = ((j >> 5) << 3) | xcd;            // 0..103
    int n0 = sx * 32;

    half8v bfr[2];
    #pragma unroll
    for (int c = 0; c < 2; ++c)
        bfr[c] = *(const half8v*)(Wt + (size_t)(n0 + c * 16 + lr) * 32 + lk);

    int tb = (y * 4 + wid) * 4;
    for (int pp = 0; pp < 4; pp += 2) {
        int tA = tb + pp;
        if (tA >= N_TILES) break;
        int mA = tA * 16, mB = mA + 16;
        half8v aA = *(const half8v*)(A + (size_t)(mA + lr) * 32 + lk);
        half8v aB = *(const half8v*)(A + (size_t)(mB + lr) * 32 + lk);
        f32x4 acc[2][2];
        #pragma unroll
        for (int i = 0; i < 2; ++i)
            #pragma unroll
            for (int c = 0; c < 2; ++c)
                acc[i][c] = (f32x4){0.f, 0.f, 0.f, 0.f};
        acc[0][0] = __builtin_amdgcn_mfma_f32_16x16x32_f16(aA, bfr[0], acc[0][0], 0, 0, 0);
        acc[0][1] = __builtin_amdgcn_mfma_f32_16x16x32_f16(aA, bfr[1], acc[0][1], 0, 0, 0);
        acc[1][0] = __builtin_amdgcn_mfma_f32_16x16x32_f16(aB, bfr[0], acc[1][0], 0, 0, 0);
        acc[1][1] = __builtin_amdgcn_mfma_f32_16x16x32_f16(aB, bfr[1], acc[1][1], 0, 0, 0);

        int rbase = (lane >> 4) * 4;
        #pragma unroll
        for (int ti = 0; ti < 2; ++ti) {
            #pragma unroll
            for (int c = 0; c < 2; ++c)
                #pragma unroll
                for (int r = 0; r < 4; ++r)
                    cst[wid][(rbase + r) * 36 + c * 16 + lr] = __float2half(acc[ti][c][r]);
            int m0 = ti ? mB : mA;
            #pragma unroll
            for (int p = 0; p < 2; ++p) {
                int row = p * 8 + (lane >> 3), hb = lane & 7;
                float2 v = *(const float2*)((const char*)&cst[wid][0] + row * 72 + hb * 8);
                *(float2*)((char*)C + ((size_t)(m0 + row) * 1024 + n0) * 2 + hb * 8) = v;
            }
        }
    }
}

// ---------------------------------------------------------------- GEMM 2: head-mean-folded, out [M,256]
// C = relu(A[M,K] @ Wt[256,K]^T + bias). B staged in LDS per k-chunk (R11-proven structure).
// bid = xcd + 8*(strip + 8*yhi); y = yhi*8+xcd -> same row-group on one XCD.
template <int K, typename OT>
__global__ __launch_bounds__(256, 2) void k_gemmo(const __half* __restrict__ A,
                                                  const __half* __restrict__ Wt,
                                                  const float* __restrict__ bias,
                                                  OT* __restrict__ C) {
    constexpr int CK  = (K > 256) ? 256 : K;    // LDS chunk cols (16KB max)
    constexpr int KC  = K / CK;
    constexpr int KSC = CK / 32;
    constexpr int CB  = CK * 2;                 // bytes per LDS col
    __shared__ __half bs[32 * CK];
    __shared__ float cst[4][16 * 36];
    int t = threadIdx.x, wid = t >> 6, lane = t & 63;
    int lr = lane & 15, lk = (lane >> 4) * 8;

    int bid = blockIdx.x;
    int xcd = bid & 7, rest = bid >> 3;
    int strip = rest & 7, yhi = rest >> 3;
    int y = yhi * 8 + xcd;                      // row-group; same y -> same XCD
    bool live = (y < 98);
    int n0 = strip * 32;
    float bv0 = bias[n0 + lr], bv1 = bias[n0 + 16 + lr];
    int tb = (y * 4 + wid) * 4;
    const int swz = (lr & 7) << 4;

    f32x4 acc[2][2][2];                          // [pair][tile][colblock]
    #pragma unroll
    for (int pi = 0; pi < 2; ++pi)
        #pragma unroll
        for (int i = 0; i < 2; ++i)
            #pragma unroll
            for (int c = 0; c < 2; ++c)
                acc[pi][i][c] = (f32x4){0.f, 0.f, 0.f, 0.f};

    for (int kc = 0; kc < KC; ++kc) {
        if (kc) __syncthreads();                 // readers of previous chunk done
        // cooperative stage: 32 cols x CK halfs, swizzled byte ^= ((col&7)<<4)
        for (int i = t * 16; i < 32 * CB; i += 256 * 16) {
            int col = i / CB, offb = i % CB;
            const char* src = (const char*)Wt + (((size_t)(n0 + col) * K + kc * CK) * 2 + offb);
            int sb = i ^ ((col & 7) << 4);
            *(float4*)((char*)bs + sb) = *(const float4*)src;
        }
        __syncthreads();
        if (!live) continue;

        #pragma unroll
        for (int pi = 0; pi < 2; ++pi) {
            int tA = tb + pi * 2;
            if (tA >= N_TILES) continue;
            int mA = tA * 16, mB = mA + 16;
            const __half* pA = A + (size_t)(mA + lr) * K + kc * CK + lk;
            const __half* pB = A + (size_t)(mB + lr) * K + kc * CK + lk;
            #pragma unroll
            for (int ks = 0; ks < KSC; ++ks) {
                half8v aA = *(const half8v*)(pA + (size_t)ks * 32);
                half8v aB = *(const half8v*)(pB + (size_t)ks * 32);
                half8v b0 = *(const half8v*)((const char*)bs + ((( 0 + lr) * CB + lk * 2 + ks * 64) ^ swz));
                half8v b1 = *(const half8v*)((const char*)bs + (((16 + lr) * CB + lk * 2 + ks * 64) ^ swz));
                acc[pi][0][0] = __builtin_amdgcn_mfma_f32_16x16x32_f16(aA, b0, acc[pi][0][0], 0, 0, 0);
                acc[pi][0][1] = __builtin_amdgcn_mfma_f32_16x16x32_f16(aA, b1, acc[pi][0][1], 0, 0, 0);
                acc[pi][1][0] = __builtin_amdgcn_mfma_f32_16x16x32_f16(aB, b0, acc[pi][1][0], 0, 0, 0);
                acc[pi][1][1] = __builtin_amdgcn_mfma_f32_16x16x32_f16(aB, b1, acc[pi][1][1], 0, 0, 0);
            }
        }
    }
    if (!live) return;

    int rbase = (lane >> 4) * 4;
    #pragma unroll
    for (int pi = 0; pi < 2; ++pi) {
        int tA = tb + pi * 2;
        if (tA >= N_TILES) continue;
        #pragma unroll
        for (int ti = 0; ti < 2; ++ti) {
            #pragma unroll
            for (int c = 0; c < 2; ++c)
                #pragma unroll
                for (int r = 0; r < 4; ++r)
                    cst[wid][(rbase + r) * 36 + c * 16 + lr] =
                        fmaxf(acc[pi][ti][c][r] + (c ? bv1 : bv0), 0.f);
            int m0 = tA * 16 + ti * 16;
            int row = lane >> 2, cg = lane & 3;   // 16 rows x 4 col-groups of 8
            const float* sp = &cst[wid][row * 36 + cg * 8];
            if constexpr (sizeof(OT) == 2) {
                __half2 o0 = __float22half2_rn(make_float2(sp[0], sp[1]));
                __half2 o1 = __float22half2_rn(make_float2(sp[2], sp[3]));
                __half2 o2 = __float22half2_rn(make_float2(sp[4], sp[5]));
                __half2 o3 = __float22half2_rn(make_float2(sp[6], sp[7]));
                float4 v = make_float4(__uint_as_float(*(unsigned*)&o0), __uint_as_float(*(unsigned*)&o1),
                                       __uint_as_float(*(unsigned*)&o2), __uint_as_float(*(unsigned*)&o3));
                *(float4*)((__half*)C + (size_t)(m0 + row) * 256 + n0 + cg * 8) = v;
            } else {
                float4 v0 = make_float4(sp[0], sp[1], sp[2], sp[3]);
                float4 v1 = make_float4(sp[4], sp[5], sp[6], sp[7]);
                float* cp = (float*)C + (size_t)(m0 + row) * 256 + n0 + cg * 8;
                *(float4*)cp = v0;
                *(float4*)(cp + 4) = v1;
            }
        }
    }
}

// ---------------------------------------------------------------- attention scalars
__global__ __launch_bounds__(256) void k_esed2(const __half* __restrict__ h1f,
                                               const float* __restrict__ wa,
                                               const float* __restrict__ wd,
                                               float* __restrict__ es,
                                               float* __restrict__ ed,
                                               int* __restrict__ mkey) {
    int n = blockIdx.x;
    int h = threadIdx.x >> 6, lane = threadIdx.x & 63;
    float s = 0.f, d2 = 0.f;
    for (int d = lane; d < 256; d += 64) {
        float v = __half2float(h1f[(size_t)n * 256 + d]);
        s  += v * wa[h * 256 + d];
        d2 += v * wd[h * 256 + d];
    }
    #pragma unroll
    for (int off = 32; off; off >>= 1) {
        s  += __shfl_down(s, off);
        d2 += __shfl_down(d2, off);
    }
    if (lane == 0) {
        es[n * 4 + h] = s; ed[n * 4 + h] = d2;
        mkey[n * 4 + h] = fkey(leaky(s + d2));
    }
}

__global__ __launch_bounds__(256) void k_mmax(const int* __restrict__ ei,
                                              const float* __restrict__ es,
                                              const float* __restrict__ ed,
                                              int* __restrict__ mkey) {
    int idx = blockIdx.x * 256 + threadIdx.x;
    if (idx >= N_EDGES * 4) return;
    int e = idx >> 2, h = idx & 3;
    int src = ei[e], dst = ei[N_EDGES + e];
    atomicMax(&mkey[dst * 4 + h], fkey(leaky(es[src * 4 + h] + ed[dst * 4 + h])));
}

__global__ __launch_bounds__(256) void k_watt(const int* __restrict__ ei,
                                              const int* __restrict__ epos,
                                              const float* __restrict__ es,
                                              const float* __restrict__ ed,
                                              const int* __restrict__ mkey,
                                              float* __restrict__ wv,
                                              float* __restrict__ den) {
    int idx = blockIdx.x * 256 + threadIdx.x;
    if (idx >= N_EDGES * 4) return;
    int e = idx >> 2, h = idx & 3;
    int src = ei[e], dst = ei[N_EDGES + e];
    float v = leaky(es[src * 4 + h] + ed[dst * 4 + h]);
    float w = __expf(v - funkey(mkey[dst * 4 + h]));
    wv[(size_t)epos[e] * 4 + h] = w;
    atomicAdd(&den[dst * 4 + h], w);
}

// ---------------------------------------------------------------- pre-GEMM aggregation
__global__ __launch_bounds__(256) void k_agg1(const int* __restrict__ rowptr,
                                              const int* __restrict__ csrc,
                                              const float* __restrict__ es,
                                              const float* __restrict__ ed,
                                              const int* __restrict__ mkey,
                                              const float* __restrict__ denb,
                                              const float* __restrict__ wv,
                                              const __half* __restrict__ h0f,
                                              __half* __restrict__ agg0) {
    int dst = blockIdx.x * 4 + (threadIdx.x >> 6);
    if (dst >= N_NODES) return;
    int lane = threadIdx.x & 63;
    int h = lane >> 4, i2 = lane & 15;
    float m = funkey(mkey[dst * 4 + h]);
    float vself = leaky(es[dst * 4 + h] + ed[dst * 4 + h]);
    float ws = __expf(vself - m);
    float dn = denb[dst * 4 + h] + ws;
    int r0 = rowptr[dst], r1 = rowptr[dst + 1];

    __half2 hv = *(const __half2*)(h0f + (size_t)dst * 32 + i2 * 2);
    float2 f = __half22float2(hv);
    float ax = ws * f.x, ay = ws * f.y;
    for (int r = r0; r < r1; ++r) {
        int src = csrc[r];
        float w = wv[(size_t)r * 4 + h];
        __half2 sv = *(const __half2*)(h0f + (size_t)src * 32 + i2 * 2);
        float2 g = __half22float2(sv);
        ax += w * g.x; ay += w * g.y;
    }
    float inv = 1.f / (dn + 1e-16f);
    *(__half2*)(agg0 + (size_t)dst * 128 + h * 32 + i2 * 2) =
        __float22half2_rn(make_float2(ax * inv, ay * inv));
}

__global__ __launch_bounds__(256) void k_agg2(const int* __restrict__ rowptr,
                                              const int* __restrict__ csrc,
                                              const float* __restrict__ es,
                                              const float* __restrict__ ed,
                                              const int* __restrict__ mkey,
                                              const float* __restrict__ denb,
                                              const float* __restrict__ wv,
                                              const __half* __restrict__ h1f,
                                              __half* __restrict__ agg1) {
    int dst = blockIdx.x * 4 + (threadIdx.x >> 6);
    if (dst >= N_NODES) return;
    int lane = threadIdx.x & 63;
    float ws[4], dn[4];
    #pragma unroll
    for (int h = 0; h < 4; ++h) {
        float m = funkey(mkey[dst * 4 + h]);
        float vself = leaky(es[dst * 4 + h] + ed[dst * 4 + h]);
        ws[h] = __expf(vself - m);
        dn[h] = denb[dst * 4 + h] + ws[h];
    }
    int r0 = rowptr[dst], r1 = rowptr[dst + 1];

    float acc[4][4];
    {
        float2 q = *(const float2*)(h1f + (size_t)dst * 256 + lane * 4);
        const __half2* hq = (const __half2*)&q;
        float2 f0 = __half22float2(hq[0]), f1 = __half22float2(hq[1]);
        #pragma unroll
        for (int h = 0; h < 4; ++h) {
            acc[h][0] = ws[h] * f0.x; acc[h][1] = ws[h] * f0.y;
            acc[h][2] = ws[h] * f1.x; acc[h][3] = ws[h] * f1.y;
        }
    }
    for (int r = r0; r < r1; ++r) {
        int src = csrc[r];
        float4 w4 = *(const float4*)(wv + (size_t)r * 4);
        float2 q = *(const float2*)(h1f + (size_t)src * 256 + lane * 4);
        const __half2* hq = (const __half2*)&q;
        float2 f0 = __half22float2(hq[0]), f1 = __half22float2(hq[1]);
        acc[0][0] += w4.x * f0.x; acc[0][1] += w4.x * f0.y; acc[0][2] += w4.x * f1.x; acc[0][3] += w4.x * f1.y;
        acc[1][0] += w4.y * f0.x; acc[1][1] += w4.y * f0.y; acc[1][2] += w4.y * f1.x; acc[1][3] += w4.y * f1.y;
        acc[2][0] += w4.z * f0.x; acc[2][1] += w4.z * f0.y; acc[2][2] += w4.z * f1.x; acc[2][3] += w4.z * f1.y;
        acc[3][0] += w4.w * f0.x; acc[3][1] += w4.w * f0.y; acc[3][2] += w4.w * f1.x; acc[3][3] += w4.w * f1.y;
    }
    #pragma unroll
    for (int h = 0; h < 4; ++h) {
        float inv = 1.f / (dn[h] + 1e-16f);
        __half2 o0 = __float22half2_rn(make_float2(acc[h][0] * inv, acc[h][1] * inv));
        __half2 o1 = __float22half2_rn(make_float2(acc[h][2] * inv, acc[h][3] * inv));
        __half2* op = (__half2*)(agg1 + (size_t)dst * 1024 + h * 256 + lane * 4);
        op[0] = o0; op[1] = o1;
    }
}

// ---------------------------------------------------------------- heads
__global__ __launch_bounds__(256) void k_wire(const int* __restrict__ wm,
                                              const float* __restrict__ h2,
                                              const float* __restrict__ ww,
                                              const float* __restrict__ wb,
                                              float* __restrict__ out) {
    int k = blockIdx.x * 4 + (threadIdx.x >> 6);
    int lane = threadIdx.x & 63;
    if (k >= KWIRE) return;
    int n = wm[k];
    float s = 0.f;
    for (int d = lane; d < 256; d += 64) s += h2[(size_t)n * 256 + d] * ww[d];
    #pragma unroll
    for (int off = 32; off; off >>= 1) s += __shfl_down(s, off);
    if (lane == 0) out[k] = s + wb[0];
}

__global__ __launch_bounds__(256) void k_pool(const float* __restrict__ h2,
                                              const int* __restrict__ batch,
                                              float* __restrict__ pooled,
                                              float* __restrict__ gcnt) {
    int n0 = blockIdx.x * POOL_NB;
    int n1 = n0 + POOL_NB; if (n1 > N_NODES) n1 = N_NODES;
    int d = threadIdx.x;
    int cur = batch[n0];
    float acc = 0.f, cnt = 0.f;
    for (int n = n0; n < n1; ++n) {
        int g = batch[n];
        if (g != cur) {
            atomicAdd(&pooled[cur * 256 + d], acc);
            if (d == 0) atomicAdd(&gcnt[cur], cnt);
            acc = 0.f; cnt = 0.f; cur = g;
        }
        acc += h2[(size_t)n * 256 + d];
        cnt += 1.f;
    }
    atomicAdd(&pooled[cur * 256 + d], acc);
    if (d == 0) atomicAdd(&gcnt[cur], cnt);
}

__global__ __launch_bounds__(256) void k_act(const float* __restrict__ pooled,
                                             const float* __restrict__ gcnt,
                                             const float* __restrict__ aw,
                                             const float* __restrict__ ab,
                                             float* __restrict__ out) {
    int u = blockIdx.x * 4 + (threadIdx.x >> 6);
    int lane = threadIdx.x & 63;
    if (u >= NGRAPH * NACT) return;
    int g = u >> 4, a = u & 15;
    float c = fmaxf(gcnt[g], 1.f);
    float s = 0.f;
    for (int d = lane; d < 256; d += 64) s += pooled[g * 256 + d] * aw[d * 16 + a];
    #pragma unroll
    for (int off = 32; off; off >>= 1) s += __shfl_down(s, off);
    if (lane == 0) out[KWIRE + u] = s / c + ab[a];
}

// ---------------------------------------------------------------- launch
extern "C" void kernel_launch(void* const* d_in, const int* in_sizes, int n_in,
                              void* d_out, int out_size, void* d_ws, size_t ws_size,
                              hipStream_t stream) {
    const float* x        = (const float*)d_in[0];
    const float* edge_attr= (const float*)d_in[1];
    const int*   wire_mask= (const int*)d_in[2];
    const int*   edge_idx = (const int*)d_in[3];
    const int*   batch    = (const int*)d_in[4];
    const float* enc_w1   = (const float*)d_in[5];
    const float* enc_b1   = (const float*)d_in[6];
    const float* enc_w2   = (const float*)d_in[7];
    const float* enc_b2   = (const float*)d_in[8];
    const float* root_w   = (const float*)d_in[9];
    const float* nn_bias  = (const float*)d_in[10];
    const float* gat1_w   = (const float*)d_in[11];
    const float* gat1_asrc= (const float*)d_in[12];
    const float* gat1_adst= (const float*)d_in[13];
    const float* gat1_b   = (const float*)d_in[14];
    const float* gat2_w   = (const float*)d_in[15];
    const float* gat2_asrc= (const float*)d_in[16];
    const float* gat2_adst= (const float*)d_in[17];
    const float* gat2_b   = (const float*)d_in[18];
    const float* wire_w   = (const float*)d_in[19];
    const float* wire_b   = (const float*)d_in[20];
    const float* act_w    = (const float*)d_in[21];
    const float* act_b    = (const float*)d_in[22];
    float* out = (float*)d_out;

    float* ws = (float*)d_ws;
    size_t off = 0;
    __half* T16   = (__half*)(ws + off); off += (size_t)M_PAD * 1024 / 2;
    __half* agg1f = (__half*)(ws + off); off += (size_t)M_PAD * 1024 / 2;
    __half* agg0f = (__half*)(ws + off); off += (size_t)M_PAD * 128 / 2;
    __half* h0f   = (__half*)(ws + off); off += (size_t)M_PAD * 32 / 2;
    __half* h1f   = (__half*)(ws + off); off += (size_t)M_PAD * 256 / 2;
    __half* xf    = (__half*)(ws + off); off += (size_t)M_PAD * 32 / 2;
    __half* hEs   = (__half*)(ws + off); off += (size_t)N_EDGES * 32 / 2;
    float* xb     = ws + off; off += 800000;
    float* agg    = ws + off; off += 800000;
    float* esb    = ws + off; off += 100000;
    float* edb    = ws + off; off += 100000;
    float* h2     = ws + off; off += (size_t)M_PAD * 256;
    float* pooled = ws + off; off += NGRAPH * 256;
    float* gcnt   = ws + off; off += NGRAPH;
    int* deg      = (int*)(ws + off); off += 25600;   // zero-region start
    int* deg2     = (int*)(ws + off); off += 25600;
    int* cursor   = (int*)(ws + off); off += 25600;
    int* cursor2  = (int*)(ws + off); off += 25600;   // zero-region end
    int* rowptr   = (int*)(ws + off); off += 25600;
    int* rowptr2  = (int*)(ws + off); off += 25600;
    int* csrc     = (int*)(ws + off); off += N_EDGES;
    int* epos     = (int*)(ws + off); off += N_EDGES;
    int* cdst     = (int*)(ws + off); off += N_EDGES;
    int* epos2    = (int*)(ws + off); off += N_EDGES;
    int* mkey     = (int*)(ws + off); off += 100000;
    float* den    = ws + off; off += 100000;
    float* wv     = ws + off; off += (size_t)N_EDGES * 4;
    __half* wtt   = (__half*)(ws + off); off += 16384;    // enc_w2 perm [1024][32]
    __half* wb1t  = (__half*)(ws + off); off += 16384;    // [256][128]
    __half* wb2t  = (__half*)(ws + off); off += 131072;   // [256][1024]
    float* wa1    = ws + off; off += 128;
    float* wd1    = ws + off; off += 128;
    float* wa2    = ws + off; off += 1024;
    float* wd2    = ws + off; off += 1024;

    const int EH = N_EDGES * 4;
    const int GBT = 3328;   // T-gemm: 8 xcd x 13 ygroups x 32 strips
    const int GBO = 832;    // out-256 gemms: 8 xcd x 8 strips x 13 yhi (y>=98 staging-only)

    // ---- CSR build ----
    hipMemsetAsync(deg, 0, 4 * 25600 * sizeof(int), stream);
    k_deg2<<<(N_EDGES + 255) / 256, 256, 0, stream>>>(edge_idx, deg, deg2);
    k_scan2<<<2, 256, 0, stream>>>(deg, rowptr, deg2, rowptr2);
    k_scatter2<<<(N_EDGES + 255) / 256, 256, 0, stream>>>(edge_idx, rowptr, rowptr2,
                                                          cursor, cursor2, csrc, epos, cdst, epos2);

    // ---- weight prep ----
    k_w2perm<<<(32 * 1024 + 255) / 256, 256, 0, stream>>>(enc_w2, wtt);
    k_wb1<<<(256 * 128 + 255) / 256, 256, 0, stream>>>(gat1_w, wb1t);
    k_wb2<<<(256 * 1024 + 255) / 256, 256, 0, stream>>>(gat2_w, wb2t);
    k_xcvt<<<(N_NODES * 32 + 255) / 256, 256, 0, stream>>>(x, enc_b2, xf, xb);
    k_wa1<<<1, 128, 0, stream>>>(gat1_w, gat1_asrc, gat1_adst, wa1, wd1);
    k_wa2<<<4, 256, 0, stream>>>(gat2_w, gat2_asrc, gat2_adst, wa2, wd2);

    // ---- NNConv ----
    hipMemsetAsync(agg, 0, 800000 * sizeof(float), stream);
    k_gemT<<<GBT, 256, 0, stream>>>(xf, wtt, T16);
    k_hedge<<<(N_EDGES + 7) / 8, 256, 0, stream>>>(edge_attr, enc_w1, enc_b1, epos2, hEs);
    k_msg2<<<(N_NODES + 7) / 8, 256, 0, stream>>>(rowptr2, cdst, hEs, T16, xb, agg);
    k_h0e<<<(N_NODES + 7) / 8, 256, 0, stream>>>(x, root_w, nn_bias, agg, rowptr,
                                                 wa1, wd1, h0f, esb, edb, mkey);

    // ---- GAT layer 1 ----
    k_mmax<<<(EH + 255) / 256, 256, 0, stream>>>(edge_idx, esb, edb, mkey);
    hipMemsetAsync(den, 0, 100000 * sizeof(float), stream);
    k_watt<<<(EH + 255) / 256, 256, 0, stream>>>(edge_idx, epos, esb, edb, mkey, wv, den);
    k_agg1<<<(N_NODES + 3) / 4, 256, 0, stream>>>(rowptr, csrc, esb, edb, mkey, den, wv, h0f, agg0f);
    k_gemmo<128, __half><<<GBO, 256, 0, stream>>>(agg0f, wb1t, gat1_b, h1f);
    k_esed2<<<N_NODES, 256, 0, stream>>>(h1f, wa2, wd2, esb, edb, mkey);

    // ---- GAT layer 2 ----
    k_mmax<<<(EH + 255) / 256, 256, 0, stream>>>(edge_idx, esb, edb, mkey);
    hipMemsetAsync(den, 0, 100000 * sizeof(float), stream);
    k_watt<<<(EH + 255) / 256, 256, 0, stream>>>(edge_idx, epos, esb, edb, mkey, wv, den);
    k_agg2<<<(N_NODES + 3) / 4, 256, 0, stream>>>(rowptr, csrc, esb, edb, mkey, den, wv, h1f, agg1f);
    k_gemmo<1024, float><<<GBO, 256, 0, stream>>>(agg1f, wb2t, gat2_b, h2);

    // ---- heads ----
    k_wire<<<KWIRE / 4, 256, 0, stream>>>(wire_mask, h2, wire_w, wire_b, out);
    hipMemsetAsync(pooled, 0, (NGRAPH * 256 + NGRAPH) * sizeof(float), stream);
    k_pool<<<(N_NODES + POOL_NB - 1) / POOL_NB, 256, 0, stream>>>(h2, batch, pooled, gcnt);
    k_act<<<NGRAPH * NACT / 4, 256, 0, stream>>>(pooled, gcnt, act_w, act_b, out);
}

// Round 18
// 537.811 us; speedup vs baseline: 1.1215x; 1.0068x over previous
//
#include <hip/hip_runtime.h>
#include <hip/hip_fp16.h>

#define N_NODES 25000
#define M_PAD   25024            // multiple of 16 (1564 tiles)
#define N_TILES 1564
#define N_PAIRS 782
#define N_EDGES 300000
#define IN_DIM  32
#define EDFD    16
#define HIDD    256
#define HEADS   4
#define NACT    16
#define NGRAPH  64
#define KWIRE   1024
#define POOL_NB 64

typedef _Float16 half8v __attribute__((ext_vector_type(8)));
typedef __attribute__((ext_vector_type(4))) float f32x4;

// ---------------------------------------------------------------- helpers
__device__ __forceinline__ float leaky(float v) { return v > 0.f ? v : 0.2f * v; }
__device__ __forceinline__ int fkey(float f) {
    int b = __float_as_int(f);
    b ^= (b >> 31) & 0x7fffffff;
    return b;
}
__device__ __forceinline__ float funkey(int b) {
    b ^= (b >> 31) & 0x7fffffff;
    return __int_as_float(b);
}

// ---------------------------------------------------------------- CSR build (both directions)
__global__ __launch_bounds__(256) void k_deg2(const int* __restrict__ ei,
                                              int* __restrict__ deg,
                                              int* __restrict__ deg2) {
    int e = blockIdx.x * 256 + threadIdx.x;
    if (e >= N_EDGES) return;
    atomicAdd(&deg[ei[N_EDGES + e]], 1);
    atomicAdd(&deg2[ei[e]], 1);
}

__global__ __launch_bounds__(256) void k_scan2(const int* __restrict__ degA, int* __restrict__ rpA,
                                               const int* __restrict__ degB, int* __restrict__ rpB) {
    const int* deg = blockIdx.x ? degB : degA;
    int* rowptr    = blockIdx.x ? rpB : rpA;
    __shared__ int part[256];
    int t = threadIdx.x;
    const int CH = 98;
    int base = t * CH;
    int s = 0;
    for (int i = 0; i < CH; ++i) {
        int idx = base + i;
        if (idx < N_NODES) s += deg[idx];
    }
    part[t] = s;
    __syncthreads();
    if (t == 0) {
        int run = 0;
        for (int i = 0; i < 256; ++i) { int v = part[i]; part[i] = run; run += v; }
    }
    __syncthreads();
    int run = part[t];
    for (int i = 0; i < CH; ++i) {
        int idx = base + i;
        if (idx < N_NODES) { rowptr[idx] = run; run += deg[idx]; }
    }
    if (N_NODES >= base && N_NODES < base + CH) rowptr[N_NODES] = run;
}

__global__ __launch_bounds__(256) void k_scatter2(const int* __restrict__ ei,
                                                  const int* __restrict__ rowptr,
                                                  const int* __restrict__ rowptr2,
                                                  int* __restrict__ cursor,
                                                  int* __restrict__ cursor2,
                                                  int* __restrict__ csrc,
                                                  int* __restrict__ epos,
                                                  int* __restrict__ cdst,
                                                  int* __restrict__ epos2) {
    int e = blockIdx.x * 256 + threadIdx.x;
    if (e >= N_EDGES) return;
    int src = ei[e], dst = ei[N_EDGES + e];
    int p1 = atomicAdd(&cursor[dst], 1);
    int r1 = rowptr[dst] + p1;
    csrc[r1] = src;
    epos[e] = r1;
    int p2 = atomicAdd(&cursor2[src], 1);
    int r2 = rowptr2[src] + p2;
    cdst[r2] = dst;
    epos2[e] = r2;
}

// ---------------------------------------------------------------- weight prep
__global__ __launch_bounds__(256) void k_w2perm(const float* __restrict__ w2,
                                                __half* __restrict__ Wt) {
    int idx = blockIdx.x * 256 + threadIdx.x;   // co*32 + i
    if (idx >= 32 * 1024) return;
    int co = idx >> 5, i = idx & 31;
    Wt[idx] = __float2half(w2[(co >> 5) * 1024 + i * 32 + (co & 31)]);
}

// head-mean-folded weights: Wb1[d][k], k=h*32+i ; value 0.25*W1[i, h*256+d]
__global__ __launch_bounds__(256) void k_wb1(const float* __restrict__ W1,
                                             __half* __restrict__ Wb) {
    int idx = blockIdx.x * 256 + threadIdx.x;   // d*128+k
    if (idx >= 256 * 128) return;
    int d = idx >> 7, k = idx & 127;
    int h = k >> 5, i = k & 31;
    Wb[idx] = __float2half(0.25f * W1[i * 1024 + h * 256 + d]);
}

// Wb2[d][k], k=h*256+i ; value 0.25*W2[i, h*256+d]
__global__ __launch_bounds__(256) void k_wb2(const float* __restrict__ W2,
                                             __half* __restrict__ Wb) {
    int idx = blockIdx.x * 256 + threadIdx.x;   // d*1024+k
    if (idx >= 256 * 1024) return;
    int d = idx >> 10, k = idx & 1023;
    int h = k >> 8, i = k & 255;
    Wb[idx] = __float2half(0.25f * W2[i * 1024 + h * 256 + d]);
}

__global__ __launch_bounds__(128) void k_wa1(const float* __restrict__ W1,
                                             const float* __restrict__ asrc,
                                             const float* __restrict__ adst,
                                             float* __restrict__ wa,
                                             float* __restrict__ wd) {
    int t = threadIdx.x;            // h*32+i
    int h = t >> 5, i = t & 31;
    float s = 0.f, sd = 0.f;
    for (int d = 0; d < 256; ++d) {
        float w = W1[i * 1024 + h * 256 + d];
        s  += w * asrc[h * 256 + d];
        sd += w * adst[h * 256 + d];
    }
    wa[t] = s; wd[t] = sd;
}

__global__ __launch_bounds__(256) void k_wa2(const float* __restrict__ W2,
                                             const float* __restrict__ asrc,
                                             const float* __restrict__ adst,
                                             float* __restrict__ wa,
                                             float* __restrict__ wd) {
    int idx = blockIdx.x * 256 + threadIdx.x;   // h*256+i
    if (idx >= 1024) return;
    int h = idx >> 8, i = idx & 255;
    float s = 0.f, sd = 0.f;
    for (int d = 0; d < 256; ++d) {
        float w = W2[i * 1024 + h * 256 + d];
        s  += w * asrc[h * 256 + d];
        sd += w * adst[h * 256 + d];
    }
    wa[idx] = s; wd[idx] = sd;
}

__global__ __launch_bounds__(256) void k_xcvt(const float* __restrict__ x,
                                              const float* __restrict__ b2,
                                              __half* __restrict__ xf,
                                              float* __restrict__ xb) {
    int idx = blockIdx.x * 256 + threadIdx.x;
    if (idx >= N_NODES * 32) return;
    int n = idx >> 5, o = idx & 31;
    xf[idx] = __float2half(x[idx]);
    float s = 0.f;
    for (int i = 0; i < 32; ++i) s += x[n * 32 + i] * b2[i * 32 + o];
    xb[idx] = s;
}

// ---------------------------------------------------------------- NNConv
__global__ __launch_bounds__(256) void k_hedge(const float* __restrict__ ea,
                                               const float* __restrict__ w1,
                                               const float* __restrict__ b1,
                                               const int* __restrict__ epos2,
                                               __half* __restrict__ hEs) {
    int t = threadIdx.x;
    int eg = t >> 5, o = t & 31;
    int e = blockIdx.x * 8 + eg;
    if (e >= N_EDGES) return;
    float a = b1[o];
    for (int k = 0; k < EDFD; ++k) a += ea[e * EDFD + k] * w1[k * 32 + o];
    hEs[(size_t)epos2[e] * 32 + o] = __float2half(fmaxf(a, 0.f));
}

__global__ __launch_bounds__(256) void k_msg2(const int* __restrict__ rowptr2,
                                              const int* __restrict__ cdst,
                                              const __half* __restrict__ hEs,
                                              const __half* __restrict__ T,
                                              const float* __restrict__ xb,
                                              float* __restrict__ agg) {
    int g = threadIdx.x >> 5, o = threadIdx.x & 31;
    int src = blockIdx.x * 8 + g;
    if (src >= N_NODES) return;
    int r0 = rowptr2[src], r1 = rowptr2[src + 1];
    if (r0 == r1) return;
    float tcol[32];
    const __half* Tp = T + (size_t)src * 1024 + o;
    #pragma unroll
    for (int j = 0; j < 32; ++j) tcol[j] = __half2float(Tp[j * 32]);
    float xbv = xb[src * 32 + o];
    for (int r = r0; r < r1; ++r) {
        int dst = cdst[r];
        const __half2* hp2 = (const __half2*)(hEs + (size_t)r * 32);
        float m = xbv;
        #pragma unroll
        for (int jj = 0; jj < 16; ++jj) {
            float2 hv = __half22float2(hp2[jj]);
            m += hv.x * tcol[2 * jj] + hv.y * tcol[2 * jj + 1];
        }
        atomicAdd(&agg[dst * 32 + o], m);
    }
}

// h0 = relu(agg/deg + x@root_w + bias) -> fp16, fused layer1 es/ed/mkey
__global__ __launch_bounds__(256) void k_h0e(const float* __restrict__ x,
                                             const float* __restrict__ root_w,
                                             const float* __restrict__ nn_bias,
                                             const float* __restrict__ agg,
                                             const int* __restrict__ rowptr,
                                             const float* __restrict__ wa,
                                             const float* __restrict__ wd,
                                             __half* __restrict__ h0f,
                                             float* __restrict__ es,
                                             float* __restrict__ ed,
                                             int* __restrict__ mkey) {
    int t = threadIdx.x;
    int ng = t >> 5, o = t & 31;
    int n = blockIdx.x * 8 + ng;
    if (n >= N_NODES) return;
    float s = nn_bias[o];
    for (int k = 0; k < IN_DIM; ++k) s += x[n * IN_DIM + k] * root_w[k * 32 + o];
    float c = fmaxf((float)(rowptr[n + 1] - rowptr[n]), 1.f);
    s += agg[n * IN_DIM + o] / c;
    float v = fmaxf(s, 0.f);
    h0f[n * IN_DIM + o] = __float2half(v);
    #pragma unroll
    for (int h = 0; h < 4; ++h) {
        float ss = v * wa[h * 32 + o];
        float dd = v * wd[h * 32 + o];
        #pragma unroll
        for (int off = 16; off; off >>= 1) {
            ss += __shfl_down(ss, off, 32);
            dd += __shfl_down(dd, off, 32);
        }
        if (o == 0) {
            es[n * 4 + h] = ss; ed[n * 4 + h] = dd;
            mkey[n * 4 + h] = fkey(leaky(ss + dd));
        }
    }
}

// ---------------------------------------------------------------- GEMM 1: T = xf @ wtt^T, out [M,1024] fp16
__global__ __launch_bounds__(256, 2) void k_gemT(const __half* __restrict__ A,
                                                 const __half* __restrict__ Wt,
                                                 __half* __restrict__ C) {
    __shared__ __half cst[4][16 * 36];
    int t = threadIdx.x, wid = t >> 6, lane = t & 63;
    int lr = lane & 15, lk = (lane >> 4) * 8;

    int bid = blockIdx.x;
    int xcd = bid & 7, j = bid >> 3;
    int sx = j & 31;
    int y = ((j >> 5) << 3) | xcd;            // 0..103
    int n0 = sx * 32;

    half8v bfr[2];
    #pragma unroll
    for (int c = 0; c < 2; ++c)
        bfr[c] = *(const half8v*)(Wt + (size_t)(n0 + c * 16 + lr) * 32 + lk);

    int tb = (y * 4 + wid) * 4;
    for (int pp = 0; pp < 4; pp += 2) {
        int tA = tb + pp;
        if (tA >= N_TILES) break;
        int mA = tA * 16, mB = mA + 16;
        half8v aA = *(const half8v*)(A + (size_t)(mA + lr) * 32 + lk);
        half8v aB = *(const half8v*)(A + (size_t)(mB + lr) * 32 + lk);
        f32x4 acc[2][2];
        #pragma unroll
        for (int i = 0; i < 2; ++i)
            #pragma unroll
            for (int c = 0; c < 2; ++c)
                acc[i][c] = (f32x4){0.f, 0.f, 0.f, 0.f};
        acc[0][0] = __builtin_amdgcn_mfma_f32_16x16x32_f16(aA, bfr[0], acc[0][0], 0, 0, 0);
        acc[0][1] = __builtin_amdgcn_mfma_f32_16x16x32_f16(aA, bfr[1], acc[0][1], 0, 0, 0);
        acc[1][0] = __builtin_amdgcn_mfma_f32_16x16x32_f16(aB, bfr[0], acc[1][0], 0, 0, 0);
        acc[1][1] = __builtin_amdgcn_mfma_f32_16x16x32_f16(aB, bfr[1], acc[1][1], 0, 0, 0);

        int rbase = (lane >> 4) * 4;
        #pragma unroll
        for (int ti = 0; ti < 2; ++ti) {
            #pragma unroll
            for (int c = 0; c < 2; ++c)
                #pragma unroll
                for (int r = 0; r < 4; ++r)
                    cst[wid][(rbase + r) * 36 + c * 16 + lr] = __float2half(acc[ti][c][r]);
            int m0 = ti ? mB : mA;
            #pragma unroll
            for (int p = 0; p < 2; ++p) {
                int row = p * 8 + (lane >> 3), hb = lane & 7;
                float2 v = *(const float2*)((const char*)&cst[wid][0] + row * 72 + hb * 8);
                *(float2*)((char*)C + ((size_t)(m0 + row) * 1024 + n0) * 2 + hb * 8) = v;
            }
        }
    }
}

// ---------------------------------------------------------------- GEMM 2: head-mean-folded, out [M,256]
// C = relu(A[M,K] @ Wt[256,K]^T + bias). B staged in LDS per 128-col chunk; one tile-pair
// per wave (grid 1600 -> ~6 blocks/CU resident, deep TLP). XCD-grouped pair-groups.
template <int K, typename OT>
__global__ __launch_bounds__(256) void k_gemmo(const __half* __restrict__ A,
                                               const __half* __restrict__ Wt,
                                               const float* __restrict__ bias,
                                               OT* __restrict__ C) {
    constexpr int CK  = 128;                    // LDS chunk cols (8KB)
    constexpr int KC  = K / CK;
    constexpr int KSC = CK / 32;
    constexpr int CB  = CK * 2;                 // bytes per LDS col
    __shared__ __half bs[32 * CK];
    __shared__ float cst[4][16 * 36];
    int t = threadIdx.x, wid = t >> 6, lane = t & 63;
    int lr = lane & 15, lk = (lane >> 4) * 8;

    int bid = blockIdx.x;
    int xcd = bid & 7, rest = bid >> 3;
    int strip = rest & 7, pg = rest >> 3;       // pair-group hi 0..24
    int y = pg * 8 + xcd;                       // pair-group 0..199; same y -> same XCD
    int p = y * 4 + wid;                        // pair index
    bool live = (p < N_PAIRS);
    int n0 = strip * 32;
    float bv0 = bias[n0 + lr], bv1 = bias[n0 + 16 + lr];
    int mA = p * 32, mB = mA + 16;
    const int swz = (lr & 7) << 4;

    f32x4 acc[2][2];                             // [tile][colblock]
    #pragma unroll
    for (int i = 0; i < 2; ++i)
        #pragma unroll
        for (int c = 0; c < 2; ++c)
            acc[i][c] = (f32x4){0.f, 0.f, 0.f, 0.f};

    for (int kc = 0; kc < KC; ++kc) {
        if (kc) __syncthreads();                 // readers of previous chunk done
        // cooperative stage: 32 cols x CK halfs, swizzled byte ^= ((col&7)<<4)
        for (int i = t * 16; i < 32 * CB; i += 256 * 16) {
            int col = i / CB, offb = i % CB;
            const char* src = (const char*)Wt + (((size_t)(n0 + col) * K + kc * CK) * 2 + offb);
            int sb = i ^ ((col & 7) << 4);
            *(float4*)((char*)bs + sb) = *(const float4*)src;
        }
        __syncthreads();
        if (!live) continue;

        const __half* pA = A + (size_t)(mA + lr) * K + kc * CK + lk;
        const __half* pB = A + (size_t)(mB + lr) * K + kc * CK + lk;
        #pragma unroll
        for (int ks = 0; ks < KSC; ++ks) {
            half8v aA = *(const half8v*)(pA + (size_t)ks * 32);
            half8v aB = *(const half8v*)(pB + (size_t)ks * 32);
            half8v b0 = *(const half8v*)((const char*)bs + ((( 0 + lr) * CB + lk * 2 + ks * 64) ^ swz));
            half8v b1 = *(const half8v*)((const char*)bs + (((16 + lr) * CB + lk * 2 + ks * 64) ^ swz));
            acc[0][0] = __builtin_amdgcn_mfma_f32_16x16x32_f16(aA, b0, acc[0][0], 0, 0, 0);
            acc[0][1] = __builtin_amdgcn_mfma_f32_16x16x32_f16(aA, b1, acc[0][1], 0, 0, 0);
            acc[1][0] = __builtin_amdgcn_mfma_f32_16x16x32_f16(aB, b0, acc[1][0], 0, 0, 0);
            acc[1][1] = __builtin_amdgcn_mfma_f32_16x16x32_f16(aB, b1, acc[1][1], 0, 0, 0);
        }
    }
    if (!live) return;

    int rbase = (lane >> 4) * 4;
    #pragma unroll
    for (int ti = 0; ti < 2; ++ti) {
        #pragma unroll
        for (int c = 0; c < 2; ++c)
            #pragma unroll
            for (int r = 0; r < 4; ++r)
                cst[wid][(rbase + r) * 36 + c * 16 + lr] =
                    fmaxf(acc[ti][c][r] + (c ? bv1 : bv0), 0.f);
        int m0 = ti ? mB : mA;
        int row = lane >> 2, cg = lane & 3;   // 16 rows x 4 col-groups of 8
        const float* sp = &cst[wid][row * 36 + cg * 8];
        if constexpr (sizeof(OT) == 2) {
            __half2 o0 = __float22half2_rn(make_float2(sp[0], sp[1]));
            __half2 o1 = __float22half2_rn(make_float2(sp[2], sp[3]));
            __half2 o2 = __float22half2_rn(make_float2(sp[4], sp[5]));
            __half2 o3 = __float22half2_rn(make_float2(sp[6], sp[7]));
            float4 v = make_float4(__uint_as_float(*(unsigned*)&o0), __uint_as_float(*(unsigned*)&o1),
                                   __uint_as_float(*(unsigned*)&o2), __uint_as_float(*(unsigned*)&o3));
            *(float4*)((__half*)C + (size_t)(m0 + row) * 256 + n0 + cg * 8) = v;
        } else {
            float4 v0 = make_float4(sp[0], sp[1], sp[2], sp[3]);
            float4 v1 = make_float4(sp[4], sp[5], sp[6], sp[7]);
            float* cp = (float*)C + (size_t)(m0 + row) * 256 + n0 + cg * 8;
            *(float4*)cp = v0;
            *(float4*)(cp + 4) = v1;
        }
    }
}

// ---------------------------------------------------------------- attention scalars
__global__ __launch_bounds__(256) void k_esed2(const __half* __restrict__ h1f,
                                               const float* __restrict__ wa,
                                               const float* __restrict__ wd,
                                               float* __restrict__ es,
                                               float* __restrict__ ed,
                                               int* __restrict__ mkey) {
    int n = blockIdx.x;
    int h = threadIdx.x >> 6, lane = threadIdx.x & 63;
    float s = 0.f, d2 = 0.f;
    for (int d = lane; d < 256; d += 64) {
        float v = __half2float(h1f[(size_t)n * 256 + d]);
        s  += v * wa[h * 256 + d];
        d2 += v * wd[h * 256 + d];
    }
    #pragma unroll
    for (int off = 32; off; off >>= 1) {
        s  += __shfl_down(s, off);
        d2 += __shfl_down(d2, off);
    }
    if (lane == 0) {
        es[n * 4 + h] = s; ed[n * 4 + h] = d2;
        mkey[n * 4 + h] = fkey(leaky(s + d2));
    }
}

__global__ __launch_bounds__(256) void k_mmax(const int* __restrict__ ei,
                                              const float* __restrict__ es,
                                              const float* __restrict__ ed,
                                              int* __restrict__ mkey) {
    int idx = blockIdx.x * 256 + threadIdx.x;
    if (idx >= N_EDGES * 4) return;
    int e = idx >> 2, h = idx & 3;
    int src = ei[e], dst = ei[N_EDGES + e];
    atomicMax(&mkey[dst * 4 + h], fkey(leaky(es[src * 4 + h] + ed[dst * 4 + h])));
}

__global__ __launch_bounds__(256) void k_watt(const int* __restrict__ ei,
                                              const int* __restrict__ epos,
                                              const float* __restrict__ es,
                                              const float* __restrict__ ed,
                                              const int* __restrict__ mkey,
                                              float* __restrict__ wv,
                                              float* __restrict__ den) {
    int idx = blockIdx.x * 256 + threadIdx.x;
    if (idx >= N_EDGES * 4) return;
    int e = idx >> 2, h = idx & 3;
    int src = ei[e], dst = ei[N_EDGES + e];
    float v = leaky(es[src * 4 + h] + ed[dst * 4 + h]);
    float w = __expf(v - funkey(mkey[dst * 4 + h]));
    wv[(size_t)epos[e] * 4 + h] = w;
    atomicAdd(&den[dst * 4 + h], w);
}

// ---------------------------------------------------------------- pre-GEMM aggregation
__global__ __launch_bounds__(256) void k_agg1(const int* __restrict__ rowptr,
                                              const int* __restrict__ csrc,
                                              const float* __restrict__ es,
                                              const float* __restrict__ ed,
                                              const int* __restrict__ mkey,
                                              const float* __restrict__ denb,
                                              const float* __restrict__ wv,
                                              const __half* __restrict__ h0f,
                                              __half* __restrict__ agg0) {
    int dst = blockIdx.x * 4 + (threadIdx.x >> 6);
    if (dst >= N_NODES) return;
    int lane = threadIdx.x & 63;
    int h = lane >> 4, i2 = lane & 15;
    float m = funkey(mkey[dst * 4 + h]);
    float vself = leaky(es[dst * 4 + h] + ed[dst * 4 + h]);
    float ws = __expf(vself - m);
    float dn = denb[dst * 4 + h] + ws;
    int r0 = rowptr[dst], r1 = rowptr[dst + 1];

    __half2 hv = *(const __half2*)(h0f + (size_t)dst * 32 + i2 * 2);
    float2 f = __half22float2(hv);
    float ax = ws * f.x, ay = ws * f.y;
    for (int r = r0; r < r1; ++r) {
        int src = csrc[r];
        float w = wv[(size_t)r * 4 + h];
        __half2 sv = *(const __half2*)(h0f + (size_t)src * 32 + i2 * 2);
        float2 g = __half22float2(sv);
        ax += w * g.x; ay += w * g.y;
    }
    float inv = 1.f / (dn + 1e-16f);
    *(__half2*)(agg0 + (size_t)dst * 128 + h * 32 + i2 * 2) =
        __float22half2_rn(make_float2(ax * inv, ay * inv));
}

__global__ __launch_bounds__(256) void k_agg2(const int* __restrict__ rowptr,
                                              const int* __restrict__ csrc,
                                              const float* __restrict__ es,
                                              const float* __restrict__ ed,
                                              const int* __restrict__ mkey,
                                              const float* __restrict__ denb,
                                              const float* __restrict__ wv,
                                              const __half* __restrict__ h1f,
                                              __half* __restrict__ agg1) {
    int dst = blockIdx.x * 4 + (threadIdx.x >> 6);
    if (dst >= N_NODES) return;
    int lane = threadIdx.x & 63;
    float ws[4], dn[4];
    #pragma unroll
    for (int h = 0; h < 4; ++h) {
        float m = funkey(mkey[dst * 4 + h]);
        float vself = leaky(es[dst * 4 + h] + ed[dst * 4 + h]);
        ws[h] = __expf(vself - m);
        dn[h] = denb[dst * 4 + h] + ws[h];
    }
    int r0 = rowptr[dst], r1 = rowptr[dst + 1];

    float acc[4][4];
    {
        float2 q = *(const float2*)(h1f + (size_t)dst * 256 + lane * 4);
        const __half2* hq = (const __half2*)&q;
        float2 f0 = __half22float2(hq[0]), f1 = __half22float2(hq[1]);
        #pragma unroll
        for (int h = 0; h < 4; ++h) {
            acc[h][0] = ws[h] * f0.x; acc[h][1] = ws[h] * f0.y;
            acc[h][2] = ws[h] * f1.x; acc[h][3] = ws[h] * f1.y;
        }
    }
    for (int r = r0; r < r1; ++r) {
        int src = csrc[r];
        float4 w4 = *(const float4*)(wv + (size_t)r * 4);
        float2 q = *(const float2*)(h1f + (size_t)src * 256 + lane * 4);
        const __half2* hq = (const __half2*)&q;
        float2 f0 = __half22float2(hq[0]), f1 = __half22float2(hq[1]);
        acc[0][0] += w4.x * f0.x; acc[0][1] += w4.x * f0.y; acc[0][2] += w4.x * f1.x; acc[0][3] += w4.x * f1.y;
        acc[1][0] += w4.y * f0.x; acc[1][1] += w4.y * f0.y; acc[1][2] += w4.y * f1.x; acc[1][3] += w4.y * f1.y;
        acc[2][0] += w4.z * f0.x; acc[2][1] += w4.z * f0.y; acc[2][2] += w4.z * f1.x; acc[2][3] += w4.z * f1.y;
        acc[3][0] += w4.w * f0.x; acc[3][1] += w4.w * f0.y; acc[3][2] += w4.w * f1.x; acc[3][3] += w4.w * f1.y;
    }
    #pragma unroll
    for (int h = 0; h < 4; ++h) {
        float inv = 1.f / (dn[h] + 1e-16f);
        __half2 o0 = __float22half2_rn(make_float2(acc[h][0] * inv, acc[h][1] * inv));
        __half2 o1 = __float22half2_rn(make_float2(acc[h][2] * inv, acc[h][3] * inv));
        __half2* op = (__half2*)(agg1 + (size_t)dst * 1024 + h * 256 + lane * 4);
        op[0] = o0; op[1] = o1;
    }
}

// ---------------------------------------------------------------- heads
__global__ __launch_bounds__(256) void k_wire(const int* __restrict__ wm,
                                              const float* __restrict__ h2,
                                              const float* __restrict__ ww,
                                              const float* __restrict__ wb,
                                              float* __restrict__ out) {
    int k = blockIdx.x * 4 + (threadIdx.x >> 6);
    int lane = threadIdx.x & 63;
    if (k >= KWIRE) return;
    int n = wm[k];
    float s = 0.f;
    for (int d = lane; d < 256; d += 64) s += h2[(size_t)n * 256 + d] * ww[d];
    #pragma unroll
    for (int off = 32; off; off >>= 1) s += __shfl_down(s, off);
    if (lane == 0) out[k] = s + wb[0];
}

__global__ __launch_bounds__(256) void k_pool(const float* __restrict__ h2,
                                              const int* __restrict__ batch,
                                              float* __restrict__ pooled,
                                              float* __restrict__ gcnt) {
    int n0 = blockIdx.x * POOL_NB;
    int n1 = n0 + POOL_NB; if (n1 > N_NODES) n1 = N_NODES;
    int d = threadIdx.x;
    int cur = batch[n0];
    float acc = 0.f, cnt = 0.f;
    for (int n = n0; n < n1; ++n) {
        int g = batch[n];
        if (g != cur) {
            atomicAdd(&pooled[cur * 256 + d], acc);
            if (d == 0) atomicAdd(&gcnt[cur], cnt);
            acc = 0.f; cnt = 0.f; cur = g;
        }
        acc += h2[(size_t)n * 256 + d];
        cnt += 1.f;
    }
    atomicAdd(&pooled[cur * 256 + d], acc);
    if (d == 0) atomicAdd(&gcnt[cur], cnt);
}

__global__ __launch_bounds__(256) void k_act(const float* __restrict__ pooled,
                                             const float* __restrict__ gcnt,
                                             const float* __restrict__ aw,
                                             const float* __restrict__ ab,
                                             float* __restrict__ out) {
    int u = blockIdx.x * 4 + (threadIdx.x >> 6);
    int lane = threadIdx.x & 63;
    if (u >= NGRAPH * NACT) return;
    int g = u >> 4, a = u & 15;
    float c = fmaxf(gcnt[g], 1.f);
    float s = 0.f;
    for (int d = lane; d < 256; d += 64) s += pooled[g * 256 + d] * aw[d * 16 + a];
    #pragma unroll
    for (int off = 32; off; off >>= 1) s += __shfl_down(s, off);
    if (lane == 0) out[KWIRE + u] = s / c + ab[a];
}

// ---------------------------------------------------------------- launch
extern "C" void kernel_launch(void* const* d_in, const int* in_sizes, int n_in,
                              void* d_out, int out_size, void* d_ws, size_t ws_size,
                              hipStream_t stream) {
    const float* x        = (const float*)d_in[0];
    const float* edge_attr= (const float*)d_in[1];
    const int*   wire_mask= (const int*)d_in[2];
    const int*   edge_idx = (const int*)d_in[3];
    const int*   batch    = (const int*)d_in[4];
    const float* enc_w1   = (const float*)d_in[5];
    const float* enc_b1   = (const float*)d_in[6];
    const float* enc_w2   = (const float*)d_in[7];
    const float* enc_b2   = (const float*)d_in[8];
    const float* root_w   = (const float*)d_in[9];
    const float* nn_bias  = (const float*)d_in[10];
    const float* gat1_w   = (const float*)d_in[11];
    const float* gat1_asrc= (const float*)d_in[12];
    const float* gat1_adst= (const float*)d_in[13];
    const float* gat1_b   = (const float*)d_in[14];
    const float* gat2_w   = (const float*)d_in[15];
    const float* gat2_asrc= (const float*)d_in[16];
    const float* gat2_adst= (const float*)d_in[17];
    const float* gat2_b   = (const float*)d_in[18];
    const float* wire_w   = (const float*)d_in[19];
    const float* wire_b   = (const float*)d_in[20];
    const float* act_w    = (const float*)d_in[21];
    const float* act_b    = (const float*)d_in[22];
    float* out = (float*)d_out;

    float* ws = (float*)d_ws;
    size_t off = 0;
    __half* T16   = (__half*)(ws + off); off += (size_t)M_PAD * 1024 / 2;
    __half* agg1f = (__half*)(ws + off); off += (size_t)M_PAD * 1024 / 2;
    __half* agg0f = (__half*)(ws + off); off += (size_t)M_PAD * 128 / 2;
    __half* h0f   = (__half*)(ws + off); off += (size_t)M_PAD * 32 / 2;
    __half* h1f   = (__half*)(ws + off); off += (size_t)M_PAD * 256 / 2;
    __half* xf    = (__half*)(ws + off); off += (size_t)M_PAD * 32 / 2;
    __half* hEs   = (__half*)(ws + off); off += (size_t)N_EDGES * 32 / 2;
    float* xb     = ws + off; off += 800000;
    float* agg    = ws + off; off += 800000;
    float* esb    = ws + off; off += 100000;
    float* edb    = ws + off; off += 100000;
    float* h2     = ws + off; off += (size_t)M_PAD * 256;
    float* pooled = ws + off; off += NGRAPH * 256;
    float* gcnt   = ws + off; off += NGRAPH;
    int* deg      = (int*)(ws + off); off += 25600;   // zero-region start
    int* deg2     = (int*)(ws + off); off += 25600;
    int* cursor   = (int*)(ws + off); off += 25600;
    int* cursor2  = (int*)(ws + off); off += 25600;   // zero-region end
    int* rowptr   = (int*)(ws + off); off += 25600;
    int* rowptr2  = (int*)(ws + off); off += 25600;
    int* csrc     = (int*)(ws + off); off += N_EDGES;
    int* epos     = (int*)(ws + off); off += N_EDGES;
    int* cdst     = (int*)(ws + off); off += N_EDGES;
    int* epos2    = (int*)(ws + off); off += N_EDGES;
    int* mkey     = (int*)(ws + off); off += 100000;
    float* den    = ws + off; off += 100000;
    float* wv     = ws + off; off += (size_t)N_EDGES * 4;
    __half* wtt   = (__half*)(ws + off); off += 16384;    // enc_w2 perm [1024][32]
    __half* wb1t  = (__half*)(ws + off); off += 16384;    // [256][128]
    __half* wb2t  = (__half*)(ws + off); off += 131072;   // [256][1024]
    float* wa1    = ws + off; off += 128;
    float* wd1    = ws + off; off += 128;
    float* wa2    = ws + off; off += 1024;
    float* wd2    = ws + off; off += 1024;

    const int EH = N_EDGES * 4;
    const int GBT = 3328;   // T-gemm: 8 xcd x 13 ygroups x 32 strips
    const int GBO = 1600;   // out-256 gemms: 8 xcd x 8 strips x 25 pg (p>=782 staging-only)

    // ---- CSR build ----
    hipMemsetAsync(deg, 0, 4 * 25600 * sizeof(int), stream);
    k_deg2<<<(N_EDGES + 255) / 256, 256, 0, stream>>>(edge_idx, deg, deg2);
    k_scan2<<<2, 256, 0, stream>>>(deg, rowptr, deg2, rowptr2);
    k_scatter2<<<(N_EDGES + 255) / 256, 256, 0, stream>>>(edge_idx, rowptr, rowptr2,
                                                          cursor, cursor2, csrc, epos, cdst, epos2);

    // ---- weight prep ----
    k_w2perm<<<(32 * 1024 + 255) / 256, 256, 0, stream>>>(enc_w2, wtt);
    k_wb1<<<(256 * 128 + 255) / 256, 256, 0, stream>>>(gat1_w, wb1t);
    k_wb2<<<(256 * 1024 + 255) / 256, 256, 0, stream>>>(gat2_w, wb2t);
    k_xcvt<<<(N_NODES * 32 + 255) / 256, 256, 0, stream>>>(x, enc_b2, xf, xb);
    k_wa1<<<1, 128, 0, stream>>>(gat1_w, gat1_asrc, gat1_adst, wa1, wd1);
    k_wa2<<<4, 256, 0, stream>>>(gat2_w, gat2_asrc, gat2_adst, wa2, wd2);

    // ---- NNConv ----
    hipMemsetAsync(agg, 0, 800000 * sizeof(float), stream);
    k_gemT<<<GBT, 256, 0, stream>>>(xf, wtt, T16);
    k_hedge<<<(N_EDGES + 7) / 8, 256, 0, stream>>>(edge_attr, enc_w1, enc_b1, epos2, hEs);
    k_msg2<<<(N_NODES + 7) / 8, 256, 0, stream>>>(rowptr2, cdst, hEs, T16, xb, agg);
    k_h0e<<<(N_NODES + 7) / 8, 256, 0, stream>>>(x, root_w, nn_bias, agg, rowptr,
                                                 wa1, wd1, h0f, esb, edb, mkey);

    // ---- GAT layer 1 ----
    k_mmax<<<(EH + 255) / 256, 256, 0, stream>>>(edge_idx, esb, edb, mkey);
    hipMemsetAsync(den, 0, 100000 * sizeof(float), stream);
    k_watt<<<(EH + 255) / 256, 256, 0, stream>>>(edge_idx, epos, esb, edb, mkey, wv, den);
    k_agg1<<<(N_NODES + 3) / 4, 256, 0, stream>>>(rowptr, csrc, esb, edb, mkey, den, wv, h0f, agg0f);
    k_gemmo<128, __half><<<GBO, 256, 0, stream>>>(agg0f, wb1t, gat1_b, h1f);
    k_esed2<<<N_NODES, 256, 0, stream>>>(h1f, wa2, wd2, esb, edb, mkey);

    // ---- GAT layer 2 ----
    k_mmax<<<(EH + 255) / 256, 256, 0, stream>>>(edge_idx, esb, edb, mkey);
    hipMemsetAsync(den, 0, 100000 * sizeof(float), stream);
    k_watt<<<(EH + 255) / 256, 256, 0, stream>>>(edge_idx, epos, esb, edb, mkey, wv, den);
    k_agg2<<<(N_NODES + 3) / 4, 256, 0, stream>>>(rowptr, csrc, esb, edb, mkey, den, wv, h1f, agg1f);
    k_gemmo<1024, float><<<GBO, 256, 0, stream>>>(agg1f, wb2t, gat2_b, h2);

    // ---- heads ----
    k_wire<<<KWIRE / 4, 256, 0, stream>>>(wire_mask, h2, wire_w, wire_b, out);
    hipMemsetAsync(pooled, 0, (NGRAPH * 256 + NGRAPH) * sizeof(float), stream);
    k_pool<<<(N_NODES + POOL_NB - 1) / POOL_NB, 256, 0, stream>>>(h2, batch, pooled, gcnt);
    k_act<<<NGRAPH * NACT / 4, 256, 0, stream>>>(pooled, gcnt, act_w, act_b, out);
}